// Round 1
// baseline (1186.540 us; speedup 1.0000x reference)
//
#include <hip/hip_runtime.h>
#include <math.h>

static constexpr int kN   = 50000;
static constexpr int kB   = 500;
static constexpr int kNPG = 100;
static constexpr int kEPG = 1600;
static constexpr int kESG = 800;
static constexpr int kF0  = 128;
static constexpr int kH1  = 256;
static constexpr int kH2  = 128;
#define BN_EPS 1e-5f

// ======================= generic tiled f32 GEMM =======================
// C[M x Nc] = act(A[M x K] @ W[K x Nc] + bias)
// BM=128, BN=64, BK=32, 256 threads, 8x4 per thread.
template<int ACT>  // 0=none 1=relu 2=sigmoid
__global__ __launch_bounds__(256)
void gemm_k(const float* __restrict__ A, const float* __restrict__ W,
            const float* __restrict__ bias, float* __restrict__ C,
            int M, int K, int Nc)
{
  __shared__ float As[32][136];  // [k][m], padded
  __shared__ float Ws[32][68];   // [k][n], padded
  const int tid = threadIdx.x;
  const int bm = blockIdx.x * 128;
  const int bn = blockIdx.y * 64;
  const int tm = (tid & 15) * 8;
  const int tn = (tid >> 4) * 4;
  float acc[8][4];
#pragma unroll
  for (int i = 0; i < 8; ++i)
#pragma unroll
    for (int j = 0; j < 4; ++j) acc[i][j] = 0.f;

  for (int k0 = 0; k0 < K; k0 += 32) {
#pragma unroll
    for (int l = 0; l < 4; ++l) {
      int idx = tid + l * 256;          // 0..1023
      int r = idx >> 3;                 // row 0..127
      int kq = (idx & 7) << 2;          // 0..28
      int gr = bm + r;
      float4 v = make_float4(0.f, 0.f, 0.f, 0.f);
      if (gr < M) v = *(const float4*)&A[(size_t)gr * K + k0 + kq];
      As[kq + 0][r] = v.x; As[kq + 1][r] = v.y;
      As[kq + 2][r] = v.z; As[kq + 3][r] = v.w;
    }
#pragma unroll
    for (int l = 0; l < 2; ++l) {
      int idx = tid + l * 256;          // 0..511
      int r = idx >> 4;                 // k 0..31
      int nq = (idx & 15) << 2;         // 0..60
      *(float4*)&Ws[r][nq] = *(const float4*)&W[(size_t)(k0 + r) * Nc + bn + nq];
    }
    __syncthreads();
#pragma unroll
    for (int kk = 0; kk < 32; ++kk) {
      float4 a0 = *(float4*)&As[kk][tm];
      float4 a1 = *(float4*)&As[kk][tm + 4];
      float4 w4 = *(float4*)&Ws[kk][tn];
      float am[8] = {a0.x, a0.y, a0.z, a0.w, a1.x, a1.y, a1.z, a1.w};
      float wn[4] = {w4.x, w4.y, w4.z, w4.w};
#pragma unroll
      for (int i = 0; i < 8; ++i)
#pragma unroll
        for (int j = 0; j < 4; ++j) acc[i][j] += am[i] * wn[j];
    }
    __syncthreads();
  }
  float4 bv = make_float4(0.f, 0.f, 0.f, 0.f);
  if (bias) bv = *(const float4*)&bias[bn + tn];
#pragma unroll
  for (int i = 0; i < 8; ++i) {
    int row = bm + tm + i;
    if (row >= M) break;
    float o0 = acc[i][0] + bv.x, o1 = acc[i][1] + bv.y;
    float o2 = acc[i][2] + bv.z, o3 = acc[i][3] + bv.w;
    if (ACT == 1) {
      o0 = fmaxf(o0, 0.f); o1 = fmaxf(o1, 0.f);
      o2 = fmaxf(o2, 0.f); o3 = fmaxf(o3, 0.f);
    } else if (ACT == 2) {
      o0 = 1.f / (1.f + expf(-o0)); o1 = 1.f / (1.f + expf(-o1));
      o2 = 1.f / (1.f + expf(-o2)); o3 = 1.f / (1.f + expf(-o3));
    }
    *(float4*)&C[(size_t)row * Nc + bn + tn] = make_float4(o0, o1, o2, o3);
  }
}

// ======================= per-graph GCN aggregation =======================
// OUT[g*100+i][c] = act( sum_j A[i][j]*H[g*100+j][c] + bias[c] )
// A built dense in LDS from the graph's edge slice:
//   A[d][s] += dinv[s]*dinv[d] per edge, A[i][i] += dinv[i]^2 (self loop).
// Stored transposed At[s][d] (stride 104) so the i-fragment read is a float4.
template<int W, int ACT>   // ACT: 0=none 1=relu
__global__ __launch_bounds__(512)
void gcn_agg_k(const float* __restrict__ H, const int* __restrict__ srcI,
               const int* __restrict__ dstI, const float* __restrict__ bias,
               float* __restrict__ OUT, int epg)
{
  extern __shared__ __align__(16) float lds[];
  float* At = lds;               // [100][104]
  float* Hs = lds + 100 * 104;   // [100][W]
  __shared__ int scnt[kNPG];
  __shared__ float sdinv[kNPG];
  const int g = blockIdx.x, tid = threadIdx.x;
  const int base = g * kNPG;
  const size_t ebase = (size_t)g * epg;

  for (int i = tid; i < 100 * 104; i += 512) At[i] = 0.f;
  if (tid < kNPG) scnt[tid] = 0;
  __syncthreads();
  for (int e = tid; e < epg; e += 512) atomicAdd(&scnt[dstI[ebase + e] - base], 1);
  __syncthreads();
  if (tid < kNPG) sdinv[tid] = rsqrtf((float)scnt[tid] + 1.f);
  __syncthreads();
  for (int e = tid; e < epg; e += 512) {
    int s = srcI[ebase + e] - base;
    int d = dstI[ebase + e] - base;
    atomicAdd(&At[s * 104 + d], sdinv[s] * sdinv[d]);
  }
  constexpr int NQ = W / 4;
  for (int idx = tid; idx < 100 * NQ; idx += 512) {
    int j = idx / NQ, cq = (idx - j * NQ) << 2;
    *(float4*)&Hs[j * W + cq] = *(const float4*)&H[(size_t)(base + j) * W + cq];
  }
  __syncthreads();
  if (tid < kNPG) At[tid * 104 + tid] += sdinv[tid] * sdinv[tid];
  __syncthreads();

  constexpr int CG = W / 4;        // c-groups (64 or 32)
  constexpr int IG = 512 / CG;     // i-groups of 8 rows (8 or 16)
  constexpr int NB = 16 / IG;      // passes so IG*NB*8 = 128 >= 100
  const int cg = tid % CG, ig = tid / CG;
  const int c0 = cg * 4;
  float4 bv = make_float4(0.f, 0.f, 0.f, 0.f);
  if (bias) bv = *(const float4*)&bias[c0];
#pragma unroll
  for (int ib = 0; ib < NB; ++ib) {
    int i0 = (ig + ib * IG) * 8;
    if (i0 >= 100) continue;
    float acc[8][4];
#pragma unroll
    for (int i = 0; i < 8; ++i)
#pragma unroll
      for (int j = 0; j < 4; ++j) acc[i][j] = 0.f;
#pragma unroll 4
    for (int j = 0; j < 100; ++j) {
      float4 a0 = *(float4*)&At[j * 104 + i0];       // broadcast (same addr per wave)
      float4 a1 = *(float4*)&At[j * 104 + i0 + 4];   // padding keeps i0+7 <= 103 safe
      float4 h4 = *(float4*)&Hs[j * W + c0];
      float am[8] = {a0.x, a0.y, a0.z, a0.w, a1.x, a1.y, a1.z, a1.w};
      float hn[4] = {h4.x, h4.y, h4.z, h4.w};
#pragma unroll
      for (int ii = 0; ii < 8; ++ii)
#pragma unroll
        for (int jj = 0; jj < 4; ++jj) acc[ii][jj] += am[ii] * hn[jj];
    }
#pragma unroll
    for (int ii = 0; ii < 8; ++ii) {
      int i = i0 + ii;
      if (i >= 100) break;
      float o0 = acc[ii][0] + bv.x, o1 = acc[ii][1] + bv.y;
      float o2 = acc[ii][2] + bv.z, o3 = acc[ii][3] + bv.w;
      if (ACT == 1) {
        o0 = fmaxf(o0, 0.f); o1 = fmaxf(o1, 0.f);
        o2 = fmaxf(o2, 0.f); o3 = fmaxf(o3, 0.f);
      }
      *(float4*)&OUT[(size_t)(base + i) * W + c0] = make_float4(o0, o1, o2, o3);
    }
  }
}

// ======================= BatchNorm over all rows (256 cols) =======================
__global__ __launch_bounds__(256)
void bn_stats_k(const float* __restrict__ X, float* __restrict__ stats, int rows)
{
  const int c = threadIdx.x;                  // 256 cols
  const int chunk = (rows + gridDim.x - 1) / gridDim.x;
  const int r0 = blockIdx.x * chunk;
  const int r1 = min(rows, r0 + chunk);
  float s = 0.f, s2 = 0.f;
  for (int r = r0; r < r1; ++r) {
    float v = X[(size_t)r * kH1 + c];
    s += v; s2 += v * v;
  }
  atomicAdd(&stats[c], s);
  atomicAdd(&stats[kH1 + c], s2);
}

__global__ __launch_bounds__(256)
void bn_apply_k(const float* __restrict__ X, const float* __restrict__ stats,
                float* __restrict__ Y, int rows)
{
  const float inv = 1.f / (float)rows;
  const int total = rows * 64;                // float4 quads, 64 per row
  for (int idx = blockIdx.x * 256 + threadIdx.x; idx < total; idx += gridDim.x * 256) {
    const int cq = (idx & 63) << 2;
    float4 v = ((const float4*)X)[idx];
    float4 o;
    { float m = stats[cq+0]*inv; float r = rsqrtf(stats[kH1+cq+0]*inv - m*m + BN_EPS); o.x = (v.x-m)*r; }
    { float m = stats[cq+1]*inv; float r = rsqrtf(stats[kH1+cq+1]*inv - m*m + BN_EPS); o.y = (v.y-m)*r; }
    { float m = stats[cq+2]*inv; float r = rsqrtf(stats[kH1+cq+2]*inv - m*m + BN_EPS); o.z = (v.z-m)*r; }
    { float m = stats[cq+3]*inv; float r = rsqrtf(stats[kH1+cq+3]*inv - m*m + BN_EPS); o.w = (v.w-m)*r; }
    ((float4*)Y)[idx] = o;
  }
}

// in-place BN over `rows` rows x 256 cols (single block; used for rows=500)
__global__ __launch_bounds__(256)
void bn_rows_k(float* __restrict__ X, int rows)
{
  const int c = threadIdx.x;
  float s = 0.f, s2 = 0.f;
  for (int r = 0; r < rows; ++r) {
    float v = X[(size_t)r * kH1 + c];
    s += v; s2 += v * v;
  }
  float m = s / (float)rows;
  float var = s2 / (float)rows - m * m;
  float rinv = rsqrtf(var + BN_EPS);
  for (int r = 0; r < rows; ++r)
    X[(size_t)r * kH1 + c] = (X[(size_t)r * kH1 + c] - m) * rinv;
}

// per-graph (100-row segment) BN over 256 cols
__global__ __launch_bounds__(256)
void seg_bn_k(const float* __restrict__ X, float* __restrict__ Y)
{
  const int g = blockIdx.x, c = threadIdx.x;
  const float* xb = X + (size_t)g * kNPG * kH1;
  float* yb = Y + (size_t)g * kNPG * kH1;
  float s = 0.f, s2 = 0.f;
  for (int r = 0; r < kNPG; ++r) {
    float v = xb[r * kH1 + c];
    s += v; s2 += v * v;
  }
  float m = s / 100.f;
  float var = s2 / 100.f - m * m;
  float rinv = rsqrtf(var + BN_EPS);
  for (int r = 0; r < kNPG; ++r)
    yb[r * kH1 + c] = (xb[r * kH1 + c] - m) * rinv;
}

// row-wise L2 normalize (128 cols); one wave per row, 4 rows per block
__global__ __launch_bounds__(256)
void l2n_k(const float* __restrict__ X, float* __restrict__ Y, int rows)
{
  const int w = threadIdx.x >> 6, lane = threadIdx.x & 63;
  const int row = blockIdx.x * 4 + w;
  if (row >= rows) return;
  float2 v = *(const float2*)&X[(size_t)row * kH2 + lane * 2];
  float ss = v.x * v.x + v.y * v.y;
#pragma unroll
  for (int o = 32; o; o >>= 1) ss += __shfl_xor(ss, o, 64);
  float inv = 1.f / fmaxf(sqrtf(ss), 1e-12f);
  *(float2*)&Y[(size_t)row * kH2 + lane * 2] = make_float2(v.x * inv, v.y * inv);
}

// per-graph column max of z and z+noise
__global__ __launch_bounds__(128)
void seg_max_k(const float* __restrict__ Z, const float* __restrict__ NOI,
               float* __restrict__ ZG, float* __restrict__ ZPG)
{
  const int g = blockIdx.x, c = threadIdx.x;   // 128 threads
  const size_t b = (size_t)g * kNPG * kH2;
  float m1 = -INFINITY, m2 = -INFINITY;
  for (int r = 0; r < kNPG; ++r) {
    float v = Z[b + r * kH2 + c];
    float n = NOI[b + r * kH2 + c];
    m1 = fmaxf(m1, v);
    m2 = fmaxf(m2, v + n);
  }
  ZG[g * kH2 + c] = m1;
  ZPG[g * kH2 + c] = m2;
}

// per-graph column mean over 100 rows (128 cols)
__global__ __launch_bounds__(128)
void mean_pool_k(const float* __restrict__ X, float* __restrict__ Y)
{
  const int g = blockIdx.x, c = threadIdx.x;
  const float* xb = X + (size_t)g * kNPG * kH2;
  float s = 0.f;
  for (int r = 0; r < kNPG; ++r) s += xb[r * kH2 + c];
  Y[g * kH2 + c] = s / 100.f;
}

// =========================================================================
extern "C" void kernel_launch(void* const* d_in, const int* in_sizes, int n_in,
                              void* d_out, int out_size, void* d_ws, size_t ws_size,
                              hipStream_t stream)
{
  const float* x        = (const float*)d_in[0];
  const int*   srcI     = (const int*)d_in[1];
  const int*   dstI     = (const int*)d_in[2];
  const float* pos_x    = (const float*)d_in[4];
  const int*   psrc     = (const int*)d_in[5];
  const int*   pdst     = (const int*)d_in[6];
  const float* neg_x    = (const float*)d_in[8];
  const int*   nsrc     = (const int*)d_in[9];
  const int*   ndst     = (const int*)d_in[10];
  const float* target_x = (const float*)d_in[12];
  const float* noise    = (const float*)d_in[13];
  const float* W_enc1   = (const float*)d_in[14];
  const float* b_enc1   = (const float*)d_in[15];
  const float* W_enc2   = (const float*)d_in[16];
  const float* b_enc2   = (const float*)d_in[17];
  const float* W_dec1   = (const float*)d_in[18];
  const float* W_dec2   = (const float*)d_in[19];
  const float* Wn1      = (const float*)d_in[20];
  const float* bn1      = (const float*)d_in[21];
  const float* Wn2      = (const float*)d_in[22];
  const float* bn2      = (const float*)d_in[23];
  const float* Ws1      = (const float*)d_in[24];
  const float* bs1      = (const float*)d_in[25];
  const float* Wp1      = (const float*)d_in[26];
  const float* bp1      = (const float*)d_in[27];
  const float* Wp2      = (const float*)d_in[28];
  const float* bp2      = (const float*)d_in[29];

  float* out  = (float*)d_out;
  float* o_z   = out;                 // N x 128
  float* o_zg  = out + 6400000;       // 500 x 128
  float* o_xr  = out + 6464000;       // N x 128
  float* o_pos = out + 12864000;      // 500 x 128
  float* o_neg = out + 12928000;
  float* o_zgm = out + 12992000;
  float* o_zpm = out + 13056000;
  float* o_tz  = out + 13120000;

  float* ws    = (float*)d_ws;
  float* bufA  = ws;                  // N x 256
  float* bufB  = ws + 12800000;       // region R2: N x 256 (or lower N x 128)
  float* bufC  = ws + 19200000;       // upper half of R2: N x 128
  float* stats = ws + 25600000;       // 512 (+pad)
  float* zpg   = ws + 25601024;       // 500 x 128
  float* t500  = zpg + 64000;         // 500 x 128
  float* t1    = t500 + 64000;        // 500 x 256
  float* t2    = t1 + 128000;         // 500 x 128
  if (ws_size < (size_t)(25921024) * sizeof(float)) return;  // scratch too small

  (void)hipFuncSetAttribute((const void*)gcn_agg_k<256, 1>,
      hipFuncAttributeMaxDynamicSharedMemorySize, 144000);
  (void)hipFuncSetAttribute((const void*)gcn_agg_k<128, 0>,
      hipFuncAttributeMaxDynamicSharedMemorySize, 92800);

  auto gg = [](int M, int Nc) {
    return dim3((unsigned)((M + 127) / 128), (unsigned)(Nc / 64), 1);
  };

  // ---------------- main encode ----------------
  gemm_k<0><<<gg(kN, kH1), 256, 0, stream>>>(x, W_enc1, nullptr, bufA, kN, kF0, kH1);
  gcn_agg_k<256, 1><<<kB, 512, 144000, stream>>>(bufA, srcI, dstI, b_enc1, bufB, kEPG);
  hipMemsetAsync(stats, 0, 512 * sizeof(float), stream);
  bn_stats_k<<<256, 256, 0, stream>>>(bufB, stats, kN);
  bn_apply_k<<<1024, 256, 0, stream>>>(bufB, stats, bufA, kN);
  gemm_k<0><<<gg(kN, kH2), 256, 0, stream>>>(bufA, W_enc2, nullptr, bufC, kN, kH1, kH2);
  gcn_agg_k<128, 0><<<kB, 512, 92800, stream>>>(bufC, srcI, dstI, b_enc2, bufB, kEPG);
  l2n_k<<<12500, 256, 0, stream>>>(bufB, o_z, kN);
  // decode
  gemm_k<1><<<gg(kN, kH1), 256, 0, stream>>>(o_z, W_dec1, nullptr, bufA, kN, kH2, kH1);
  gemm_k<2><<<gg(kN, kF0), 256, 0, stream>>>(bufA, W_dec2, nullptr, o_xr, kN, kH1, kF0);
  // pooling + projection heads
  seg_max_k<<<kB, 128, 0, stream>>>(o_z, noise, o_zg, zpg);
  gemm_k<1><<<gg(kB, kH2), 256, 0, stream>>>(o_zg, Wp1, bp1, t500, kB, kH2, kH2);
  gemm_k<0><<<gg(kB, kH2), 256, 0, stream>>>(t500, Wp2, bp2, o_zgm, kB, kH2, kH2);
  gemm_k<1><<<gg(kB, kH2), 256, 0, stream>>>(zpg, Wp1, bp1, t500, kB, kH2, kH2);
  gemm_k<0><<<gg(kB, kH2), 256, 0, stream>>>(t500, Wp2, bp2, o_zpm, kB, kH2, kH2);

  // ---------------- positive subgraphs ----------------
  gemm_k<0><<<gg(kN, kH1), 256, 0, stream>>>(pos_x, Ws1, nullptr, bufA, kN, kF0, kH1);
  gcn_agg_k<256, 1><<<kB, 512, 144000, stream>>>(bufA, psrc, pdst, bs1, bufB, kESG);
  seg_bn_k<<<kB, 256, 0, stream>>>(bufB, bufA);
  gemm_k<0><<<gg(kN, kH2), 256, 0, stream>>>(bufA, W_enc2, nullptr, bufC, kN, kH1, kH2);
  gcn_agg_k<128, 0><<<kB, 512, 92800, stream>>>(bufC, psrc, pdst, b_enc2, bufB, kESG);
  l2n_k<<<12500, 256, 0, stream>>>(bufB, bufC, kN);
  mean_pool_k<<<kB, 128, 0, stream>>>(bufC, o_pos);

  // ---------------- negative subgraphs ----------------
  gemm_k<0><<<gg(kN, kH1), 256, 0, stream>>>(neg_x, Ws1, nullptr, bufA, kN, kF0, kH1);
  gcn_agg_k<256, 1><<<kB, 512, 144000, stream>>>(bufA, nsrc, ndst, bs1, bufB, kESG);
  seg_bn_k<<<kB, 256, 0, stream>>>(bufB, bufA);
  gemm_k<0><<<gg(kN, kH2), 256, 0, stream>>>(bufA, W_enc2, nullptr, bufC, kN, kH1, kH2);
  gcn_agg_k<128, 0><<<kB, 512, 92800, stream>>>(bufC, nsrc, ndst, b_enc2, bufB, kESG);
  l2n_k<<<12500, 256, 0, stream>>>(bufB, bufC, kN);
  mean_pool_k<<<kB, 128, 0, stream>>>(bufC, o_neg);

  // ---------------- target node encoder ----------------
  gemm_k<1><<<gg(kB, kH1), 256, 0, stream>>>(target_x, Wn1, bn1, t1, kB, kF0, kH1);
  bn_rows_k<<<1, 256, 0, stream>>>(t1, kB);
  gemm_k<0><<<gg(kB, kH2), 256, 0, stream>>>(t1, Wn2, bn2, t2, kB, kH1, kH2);
  l2n_k<<<125, 256, 0, stream>>>(t2, o_tz, kB);

  (void)in_sizes; (void)n_in; (void)out_size;
}

// Round 5
// 684.084 us; speedup vs baseline: 1.7345x; 1.7345x over previous
//
#include <hip/hip_runtime.h>
#include <math.h>

static constexpr int kN   = 50000;
static constexpr int kB   = 500;
static constexpr int kNPG = 100;
static constexpr int kEPG = 1600;
static constexpr int kESG = 800;
static constexpr int kF0  = 128;
static constexpr int kH1  = 256;
static constexpr int kH2  = 128;
#define BN_EPS 1e-5f

typedef _Float16 half8 __attribute__((ext_vector_type(8)));
typedef __attribute__((ext_vector_type(4))) float f32x4;

// ================= fp16 MFMA GEMM (big M) =================
// C[M x Nc] = act(A[M x K] @ W[K x Nc]); A fp32 (optionally BN-transformed per
// column k during staging: (a - mean[k]) * rinv[k]), W fp32 gathered from L2.
// Both converted to fp16 in registers (2^-11 quantization; all values
// range-safe for fp16). BM=128, BN=128, BK=32, 4 waves, each wave 64x64 via
// 4x4 frags of mfma_f32_16x16x32_f16.
// LDS layout [kg][row][8]: fragment ds_read_b128 conflict-free.
// NOTE: A and C must NOT alias/overlap — C rows are written while other
// blocks still read A rows (this race was the round-2..4 failure).
template<int ACT, int TRANS>   // ACT 0=none 1=relu 2=sigmoid
__global__ __launch_bounds__(256)
void gemm_mfma_k(const float* __restrict__ A, const float* __restrict__ W,
                 const float* __restrict__ tr, float* __restrict__ C,
                 int M, int K, int Nc)
{
  __shared__ alignas(16) _Float16 Ash[4096];   // 8 KB
  __shared__ alignas(16) _Float16 Bsh[4096];   // 8 KB
  const int tid = threadIdx.x;
  const int lane = tid & 63;
  const int l15 = lane & 15, lg = lane >> 4;
  const int wave = tid >> 6;
  const int wm = wave >> 1, wn = wave & 1;
  const int bm = blockIdx.x * 128;
  const int bn = blockIdx.y * 128;
  f32x4 acc[4][4];
#pragma unroll
  for (int m = 0; m < 4; ++m)
#pragma unroll
    for (int n = 0; n < 4; ++n) acc[m][n] = (f32x4){0.f, 0.f, 0.f, 0.f};

  for (int k0 = 0; k0 < K; k0 += 32) {
    if (k0) __syncthreads();
#pragma unroll
    for (int h = 0; h < 2; ++h) {
      int p = tid + h * 256;          // 512 (row,kg) pairs
      int r = p >> 2, kg = p & 3;
      int kb = k0 + kg * 8;
      // ---- A tile (row r): fp32 -> (optional BN) -> fp16
      float va[8] = {0.f, 0.f, 0.f, 0.f, 0.f, 0.f, 0.f, 0.f};
      if (bm + r < M) {
        const float* s = &A[(size_t)(bm + r) * K + kb];
        float4 u0 = *(const float4*)s, u1 = *(const float4*)(s + 4);
        va[0] = u0.x; va[1] = u0.y; va[2] = u0.z; va[3] = u0.w;
        va[4] = u1.x; va[5] = u1.y; va[6] = u1.z; va[7] = u1.w;
      }
      if (TRANS) {
#pragma unroll
        for (int j = 0; j < 8; ++j) va[j] = (va[j] - tr[kb + j]) * tr[256 + kb + j];
      }
      half8 sa;
#pragma unroll
      for (int j = 0; j < 8; ++j) sa[j] = (_Float16)va[j];
      *(half8*)&Ash[(kg * 128 + r) * 8] = sa;
      // ---- B tile (col r): gather W[k][bn+r] (weights, L2-hot)
      half8 sb;
#pragma unroll
      for (int j = 0; j < 8; ++j) sb[j] = (_Float16)W[(size_t)(kb + j) * Nc + bn + r];
      *(half8*)&Bsh[(kg * 128 + r) * 8] = sb;
    }
    __syncthreads();
    half8 aF[4], bF[4];
#pragma unroll
    for (int m = 0; m < 4; ++m)
      aF[m] = *(const half8*)&Ash[(lg * 128 + wm * 64 + m * 16 + l15) * 8];
#pragma unroll
    for (int n = 0; n < 4; ++n)
      bF[n] = *(const half8*)&Bsh[(lg * 128 + wn * 64 + n * 16 + l15) * 8];
#pragma unroll
    for (int m = 0; m < 4; ++m)
#pragma unroll
      for (int n = 0; n < 4; ++n)
        acc[m][n] = __builtin_amdgcn_mfma_f32_16x16x32_f16(aF[m], bF[n], acc[m][n], 0, 0, 0);
  }
  // epilogue: C/D layout col=lane&15, row=(lane>>4)*4+q (dtype-independent)
#pragma unroll
  for (int m = 0; m < 4; ++m) {
    int row_b = bm + wm * 64 + m * 16 + lg * 4;
#pragma unroll
    for (int q = 0; q < 4; ++q) {
      int row = row_b + q;
      if (row >= M) continue;
#pragma unroll
      for (int n = 0; n < 4; ++n) {
        float v = acc[m][n][q];
        if (ACT == 1) v = fmaxf(v, 0.f);
        else if (ACT == 2) v = 1.f / (1.f + expf(-v));
        C[(size_t)row * Nc + bn + wn * 64 + n * 16 + l15] = v;
      }
    }
  }
}

// ======================= small-M tiled f32 GEMM (M=500 paths) =======================
template<int ACT>  // 0=none 1=relu 2=sigmoid
__global__ __launch_bounds__(256)
void gemm_k(const float* __restrict__ A, const float* __restrict__ W,
            const float* __restrict__ bias, float* __restrict__ C,
            int M, int K, int Nc)
{
  __shared__ float As[32][136];
  __shared__ float Ws[32][68];
  const int tid = threadIdx.x;
  const int bm = blockIdx.x * 128;
  const int bn = blockIdx.y * 64;
  const int tm = (tid & 15) * 8;
  const int tn = (tid >> 4) * 4;
  float acc[8][4];
#pragma unroll
  for (int i = 0; i < 8; ++i)
#pragma unroll
    for (int j = 0; j < 4; ++j) acc[i][j] = 0.f;

  for (int k0 = 0; k0 < K; k0 += 32) {
#pragma unroll
    for (int l = 0; l < 4; ++l) {
      int idx = tid + l * 256;
      int r = idx >> 3;
      int kq = (idx & 7) << 2;
      int gr = bm + r;
      float4 v = make_float4(0.f, 0.f, 0.f, 0.f);
      if (gr < M) v = *(const float4*)&A[(size_t)gr * K + k0 + kq];
      As[kq + 0][r] = v.x; As[kq + 1][r] = v.y;
      As[kq + 2][r] = v.z; As[kq + 3][r] = v.w;
    }
#pragma unroll
    for (int l = 0; l < 2; ++l) {
      int idx = tid + l * 256;
      int r = idx >> 4;
      int nq = (idx & 15) << 2;
      *(float4*)&Ws[r][nq] = *(const float4*)&W[(size_t)(k0 + r) * Nc + bn + nq];
    }
    __syncthreads();
#pragma unroll
    for (int kk = 0; kk < 32; ++kk) {
      float4 a0 = *(float4*)&As[kk][tm];
      float4 a1 = *(float4*)&As[kk][tm + 4];
      float4 w4 = *(float4*)&Ws[kk][tn];
      float am[8] = {a0.x, a0.y, a0.z, a0.w, a1.x, a1.y, a1.z, a1.w};
      float wn4[4] = {w4.x, w4.y, w4.z, w4.w};
#pragma unroll
      for (int i = 0; i < 8; ++i)
#pragma unroll
        for (int j = 0; j < 4; ++j) acc[i][j] += am[i] * wn4[j];
    }
    __syncthreads();
  }
  float4 bv = make_float4(0.f, 0.f, 0.f, 0.f);
  if (bias) bv = *(const float4*)&bias[bn + tn];
#pragma unroll
  for (int i = 0; i < 8; ++i) {
    int row = bm + tm + i;
    if (row >= M) break;
    float o0 = acc[i][0] + bv.x, o1 = acc[i][1] + bv.y;
    float o2 = acc[i][2] + bv.z, o3 = acc[i][3] + bv.w;
    if (ACT == 1) {
      o0 = fmaxf(o0, 0.f); o1 = fmaxf(o1, 0.f);
      o2 = fmaxf(o2, 0.f); o3 = fmaxf(o3, 0.f);
    } else if (ACT == 2) {
      o0 = 1.f / (1.f + expf(-o0)); o1 = 1.f / (1.f + expf(-o1));
      o2 = 1.f / (1.f + expf(-o2)); o3 = 1.f / (1.f + expf(-o3));
    }
    *(float4*)&C[(size_t)row * Nc + bn + tn] = make_float4(o0, o1, o2, o3);
  }
}

// ======================= per-graph GCN aggregation =======================
// Deterministic: each At cell (s,d) only ever receives identical addends
// (dinv[s]*dinv[d]); serialized same-address atomic adds of an identical
// value give one unique result regardless of order.
template<int W, int ACT>   // ACT: 0=none 1=relu
__global__ __launch_bounds__(512)
void gcn_agg_k(const float* __restrict__ H, const int* __restrict__ srcI,
               const int* __restrict__ dstI, const float* __restrict__ bias,
               float* __restrict__ OUT, int epg)
{
  extern __shared__ __align__(16) float lds[];
  float* At = lds;               // [100][104] (transposed: At[s][d])
  float* Hs = lds + 100 * 104;   // [100][W]
  __shared__ int scnt[kNPG];
  __shared__ float sdinv[kNPG];
  const int g = blockIdx.x, tid = threadIdx.x;
  const int base = g * kNPG;
  const size_t ebase = (size_t)g * epg;

  for (int i = tid; i < 100 * 104; i += 512) At[i] = 0.f;
  if (tid < kNPG) scnt[tid] = 0;
  __syncthreads();
  for (int e = tid; e < epg; e += 512) atomicAdd(&scnt[dstI[ebase + e] - base], 1);
  __syncthreads();
  if (tid < kNPG) sdinv[tid] = rsqrtf((float)scnt[tid] + 1.f);
  __syncthreads();
  for (int e = tid; e < epg; e += 512) {
    int s = srcI[ebase + e] - base;
    int d = dstI[ebase + e] - base;
    atomicAdd(&At[s * 104 + d], sdinv[s] * sdinv[d]);
  }
  constexpr int NQ = W / 4;
  for (int idx = tid; idx < 100 * NQ; idx += 512) {
    int j = idx / NQ, cq = (idx - j * NQ) << 2;
    *(float4*)&Hs[j * W + cq] = *(const float4*)&H[(size_t)(base + j) * W + cq];
  }
  __syncthreads();
  if (tid < kNPG) At[tid * 104 + tid] += sdinv[tid] * sdinv[tid];
  __syncthreads();

  constexpr int CG = W / 4;
  constexpr int IG = 512 / CG;
  constexpr int NB = 16 / IG;
  const int cg = tid % CG, ig = tid / CG;
  const int c0 = cg * 4;
  float4 bv = make_float4(0.f, 0.f, 0.f, 0.f);
  if (bias) bv = *(const float4*)&bias[c0];
#pragma unroll
  for (int ib = 0; ib < NB; ++ib) {
    int i0 = (ig + ib * IG) * 8;
    if (i0 >= 100) continue;
    float acc[8][4];
#pragma unroll
    for (int i = 0; i < 8; ++i)
#pragma unroll
      for (int j = 0; j < 4; ++j) acc[i][j] = 0.f;
#pragma unroll 4
    for (int j = 0; j < 100; ++j) {
      float4 a0 = *(float4*)&At[j * 104 + i0];
      float4 a1 = *(float4*)&At[j * 104 + i0 + 4];
      float4 h4 = *(float4*)&Hs[j * W + c0];
      float am[8] = {a0.x, a0.y, a0.z, a0.w, a1.x, a1.y, a1.z, a1.w};
      float hn[4] = {h4.x, h4.y, h4.z, h4.w};
#pragma unroll
      for (int ii = 0; ii < 8; ++ii)
#pragma unroll
        for (int jj = 0; jj < 4; ++jj) acc[ii][jj] += am[ii] * hn[jj];
    }
#pragma unroll
    for (int ii = 0; ii < 8; ++ii) {
      int i = i0 + ii;
      if (i >= 100) break;
      float o0 = acc[ii][0] + bv.x, o1 = acc[ii][1] + bv.y;
      float o2 = acc[ii][2] + bv.z, o3 = acc[ii][3] + bv.w;
      if (ACT == 1) {
        o0 = fmaxf(o0, 0.f); o1 = fmaxf(o1, 0.f);
        o2 = fmaxf(o2, 0.f); o3 = fmaxf(o3, 0.f);
      }
      *(float4*)&OUT[(size_t)(base + i) * W + c0] = make_float4(o0, o1, o2, o3);
    }
  }
}

// ============ deterministic BatchNorm stats (50000 x 256), 2-stage ============
__global__ __launch_bounds__(256)
void bn_part_k(const float* __restrict__ X, float* __restrict__ P)
{
  const int b = blockIdx.x, c = threadIdx.x;
  const float* xb = X + (size_t)b * 250 * kH1;
  float s = 0.f, s2 = 0.f;
  for (int r = 0; r < 250; ++r) {
    float v = xb[(size_t)r * kH1 + c];
    s += v; s2 += v * v;
  }
  P[b * 512 + c] = s;
  P[b * 512 + 256 + c] = s2;
}
__global__ __launch_bounds__(256)
void bn_red_k(const float* __restrict__ P, float* __restrict__ stats)
{
  const int c = threadIdx.x;
  float s = 0.f, s2 = 0.f;
  for (int b = 0; b < 200; ++b) {
    s  += P[b * 512 + c];
    s2 += P[b * 512 + 256 + c];
  }
  float m = s / (float)kN;
  float v = s2 / (float)kN - m * m;
  stats[512 + c] = m;
  stats[768 + c] = rsqrtf(v + BN_EPS);
}

// column-parallel BN, in place: X[rows][cols], one block (64 thr) per column
__global__ __launch_bounds__(64)
void bn_cols_k(float* __restrict__ X, int rows, int cols)
{
  const int c = blockIdx.x, t = threadIdx.x;
  float s = 0.f, s2 = 0.f;
  for (int r = t; r < rows; r += 64) {
    float v = X[(size_t)r * cols + c];
    s += v; s2 += v * v;
  }
#pragma unroll
  for (int o = 32; o; o >>= 1) { s += __shfl_xor(s, o, 64); s2 += __shfl_xor(s2, o, 64); }
  float m = s / (float)rows;
  float var = s2 / (float)rows - m * m;
  float rinv = rsqrtf(var + BN_EPS);
  for (int r = t; r < rows; r += 64)
    X[(size_t)r * cols + c] = (X[(size_t)r * cols + c] - m) * rinv;
}

// per-graph (100-row segment) BN over 256 cols
__global__ __launch_bounds__(256)
void seg_bn_k(const float* __restrict__ X, float* __restrict__ Y)
{
  const int g = blockIdx.x, c = threadIdx.x;
  const float* xb = X + (size_t)g * kNPG * kH1;
  float* yb = Y + (size_t)g * kNPG * kH1;
  float s = 0.f, s2 = 0.f;
  for (int r = 0; r < kNPG; ++r) {
    float v = xb[r * kH1 + c];
    s += v; s2 += v * v;
  }
  float m = s / 100.f;
  float var = s2 / 100.f - m * m;
  float rinv = rsqrtf(var + BN_EPS);
  for (int r = 0; r < kNPG; ++r)
    yb[r * kH1 + c] = (xb[r * kH1 + c] - m) * rinv;
}

// row-wise L2 normalize (128 cols)
__global__ __launch_bounds__(256)
void l2n_k(const float* __restrict__ X, float* __restrict__ Y, int rows)
{
  const int w = threadIdx.x >> 6, lane = threadIdx.x & 63;
  const int row = blockIdx.x * 4 + w;
  if (row >= rows) return;
  float2 v = *(const float2*)&X[(size_t)row * kH2 + lane * 2];
  float ss = v.x * v.x + v.y * v.y;
#pragma unroll
  for (int o = 32; o; o >>= 1) ss += __shfl_xor(ss, o, 64);
  float inv = 1.f / fmaxf(sqrtf(ss), 1e-12f);
  *(float2*)&Y[(size_t)row * kH2 + lane * 2] = make_float2(v.x * inv, v.y * inv);
}

__global__ __launch_bounds__(128)
void seg_max_k(const float* __restrict__ Z, const float* __restrict__ NOI,
               float* __restrict__ ZG, float* __restrict__ ZPG)
{
  const int g = blockIdx.x, c = threadIdx.x;
  const size_t b = (size_t)g * kNPG * kH2;
  float m1 = -INFINITY, m2 = -INFINITY;
  for (int r = 0; r < kNPG; ++r) {
    float v = Z[b + r * kH2 + c];
    float n = NOI[b + r * kH2 + c];
    m1 = fmaxf(m1, v);
    m2 = fmaxf(m2, v + n);
  }
  ZG[g * kH2 + c] = m1;
  ZPG[g * kH2 + c] = m2;
}

__global__ __launch_bounds__(128)
void mean_pool_k(const float* __restrict__ X, float* __restrict__ Y)
{
  const int g = blockIdx.x, c = threadIdx.x;
  const float* xb = X + (size_t)g * kNPG * kH2;
  float s = 0.f;
  for (int r = 0; r < kNPG; ++r) s += xb[r * kH2 + c];
  Y[g * kH2 + c] = s / 100.f;
}

// =========================================================================
extern "C" void kernel_launch(void* const* d_in, const int* in_sizes, int n_in,
                              void* d_out, int out_size, void* d_ws, size_t ws_size,
                              hipStream_t stream)
{
  const float* x        = (const float*)d_in[0];
  const int*   srcI     = (const int*)d_in[1];
  const int*   dstI     = (const int*)d_in[2];
  const float* pos_x    = (const float*)d_in[4];
  const int*   psrc     = (const int*)d_in[5];
  const int*   pdst     = (const int*)d_in[6];
  const float* neg_x    = (const float*)d_in[8];
  const int*   nsrc     = (const int*)d_in[9];
  const int*   ndst     = (const int*)d_in[10];
  const float* target_x = (const float*)d_in[12];
  const float* noise    = (const float*)d_in[13];
  const float* W_enc1   = (const float*)d_in[14];
  const float* b_enc1   = (const float*)d_in[15];
  const float* W_enc2   = (const float*)d_in[16];
  const float* b_enc2   = (const float*)d_in[17];
  const float* W_dec1   = (const float*)d_in[18];
  const float* W_dec2   = (const float*)d_in[19];
  const float* Wn1      = (const float*)d_in[20];
  const float* bn1      = (const float*)d_in[21];
  const float* Wn2      = (const float*)d_in[22];
  const float* bn2      = (const float*)d_in[23];
  const float* Ws1      = (const float*)d_in[24];
  const float* bs1      = (const float*)d_in[25];
  const float* Wp1      = (const float*)d_in[26];
  const float* bp1      = (const float*)d_in[27];
  const float* Wp2      = (const float*)d_in[28];
  const float* bp2      = (const float*)d_in[29];

  float* out  = (float*)d_out;
  float* o_z   = out;                 // N x 128
  float* o_zg  = out + 6400000;       // 500 x 128
  float* o_xr  = out + 6464000;       // N x 128
  float* o_pos = out + 12864000;      // 500 x 128
  float* o_neg = out + 12928000;
  float* o_zgm = out + 12992000;
  float* o_zpm = out + 13056000;
  float* o_tz  = out + 13120000;

  // WORKSPACE MAP. CAUTION: bufB as N x 256 spans [12800000, 25600000) which
  // OVERLAPS bufC [19200000, 25600000). Rule: never have one kernel read
  // bufB(Nx256) while writing bufC (that was the r2-r4 race). bufC may only
  // be used when bufB's 256-wide content is dead, or when bufB is 128-wide
  // ([12800000,19200000), disjoint).
  float* ws    = (float*)d_ws;
  float* bufA  = ws;                  // N x 256
  float* bufB  = ws + 12800000;       // N x 256 region
  float* bufC  = ws + 19200000;       // N x 128 (overlaps bufB rows 25000+)
  float* stats = ws + 25600000;       // 1024 floats: [512..768)=mean [768..1024)=rinv
  float* zpg   = ws + 25601024;
  float* t500  = zpg + 64000;
  float* t1    = t500 + 64000;        // 500 x 256
  float* t2    = t1 + 128000;         // 500 x 128
  float* pstat = bufA;                // 200*512 floats; bufA is dead there and
                                      // bn_red consumes it before bufA's next write
  if (ws_size < (size_t)(25921024) * sizeof(float)) return;

  (void)hipFuncSetAttribute((const void*)gcn_agg_k<256, 1>,
      hipFuncAttributeMaxDynamicSharedMemorySize, 144000);
  (void)hipFuncSetAttribute((const void*)gcn_agg_k<128, 0>,
      hipFuncAttributeMaxDynamicSharedMemorySize, 92800);

  const dim3 gB(391, 2);   // M=50000, Nc=256
  const dim3 gC(391, 1);   // M=50000, Nc=128
  auto gg = [](int M, int Nc) {
    return dim3((unsigned)((M + 127) / 128), (unsigned)(Nc / 64), 1);
  };

  // ---------------- main encode ----------------
  gemm_mfma_k<0, 0><<<gB, 256, 0, stream>>>(x, W_enc1, nullptr, bufA, kN, kF0, kH1);
  gcn_agg_k<256, 1><<<kB, 512, 144000, stream>>>(bufA, srcI, dstI, b_enc1, bufB, kEPG);
  bn_part_k<<<200, 256, 0, stream>>>(bufB, pstat);          // pstat=bufA (dead)
  bn_red_k<<<1, 256, 0, stream>>>(pstat, stats);
  // reads bufB (N x 256) -> writes bufA (N x 128): fully disjoint (race fix)
  gemm_mfma_k<0, 1><<<gC, 256, 0, stream>>>(bufB, W_enc2, stats + 512, bufA, kN, kH1, kH2);
  gcn_agg_k<128, 0><<<kB, 512, 92800, stream>>>(bufA, srcI, dstI, b_enc2, bufB, kEPG);
  l2n_k<<<12500, 256, 0, stream>>>(bufB, o_z, kN);
  // decode
  gemm_mfma_k<1, 0><<<gB, 256, 0, stream>>>(o_z, W_dec1, nullptr, bufA, kN, kH2, kH1);
  gemm_mfma_k<2, 0><<<gC, 256, 0, stream>>>(bufA, W_dec2, nullptr, o_xr, kN, kH1, kF0);
  // pooling + projection heads
  seg_max_k<<<kB, 128, 0, stream>>>(o_z, noise, o_zg, zpg);
  gemm_k<1><<<gg(kB, kH2), 256, 0, stream>>>(o_zg, Wp1, bp1, t500, kB, kH2, kH2);
  gemm_k<0><<<gg(kB, kH2), 256, 0, stream>>>(t500, Wp2, bp2, o_zgm, kB, kH2, kH2);
  gemm_k<1><<<gg(kB, kH2), 256, 0, stream>>>(zpg, Wp1, bp1, t500, kB, kH2, kH2);
  gemm_k<0><<<gg(kB, kH2), 256, 0, stream>>>(t500, Wp2, bp2, o_zpm, kB, kH2, kH2);

  // ---------------- positive subgraphs ----------------
  gemm_mfma_k<0, 0><<<gB, 256, 0, stream>>>(pos_x, Ws1, nullptr, bufA, kN, kF0, kH1);
  gcn_agg_k<256, 1><<<kB, 512, 144000, stream>>>(bufA, psrc, pdst, bs1, bufB, kESG);
  seg_bn_k<<<kB, 256, 0, stream>>>(bufB, bufA);             // bufB(256) now dead
  // reads bufA -> writes bufC: disjoint (bufB's overlapping content dead)
  gemm_mfma_k<0, 0><<<gC, 256, 0, stream>>>(bufA, W_enc2, nullptr, bufC, kN, kH1, kH2);
  gcn_agg_k<128, 0><<<kB, 512, 92800, stream>>>(bufC, psrc, pdst, b_enc2, bufB, kESG);
  l2n_k<<<12500, 256, 0, stream>>>(bufB, bufC, kN);         // 128-wide: disjoint
  mean_pool_k<<<kB, 128, 0, stream>>>(bufC, o_pos);

  // ---------------- negative subgraphs ----------------
  gemm_mfma_k<0, 0><<<gB, 256, 0, stream>>>(neg_x, Ws1, nullptr, bufA, kN, kF0, kH1);
  gcn_agg_k<256, 1><<<kB, 512, 144000, stream>>>(bufA, nsrc, ndst, bs1, bufB, kESG);
  seg_bn_k<<<kB, 256, 0, stream>>>(bufB, bufA);
  gemm_mfma_k<0, 0><<<gC, 256, 0, stream>>>(bufA, W_enc2, nullptr, bufC, kN, kH1, kH2);
  gcn_agg_k<128, 0><<<kB, 512, 92800, stream>>>(bufC, nsrc, ndst, b_enc2, bufB, kESG);
  l2n_k<<<12500, 256, 0, stream>>>(bufB, bufC, kN);
  mean_pool_k<<<kB, 128, 0, stream>>>(bufC, o_neg);

  // ---------------- target node encoder ----------------
  gemm_k<1><<<gg(kB, kH1), 256, 0, stream>>>(target_x, Wn1, bn1, t1, kB, kF0, kH1);
  bn_cols_k<<<256, 64, 0, stream>>>(t1, kB, kH1);
  gemm_k<0><<<gg(kB, kH2), 256, 0, stream>>>(t1, Wn2, bn2, t2, kB, kH1, kH2);
  l2n_k<<<125, 256, 0, stream>>>(t2, o_tz, kB);

  (void)in_sizes; (void)n_in; (void)out_size;
}

// Round 6
// 601.059 us; speedup vs baseline: 1.9741x; 1.1381x over previous
//
#include <hip/hip_runtime.h>
#include <math.h>

static constexpr int kN   = 50000;
static constexpr int kB   = 500;
static constexpr int kNPG = 100;
static constexpr int kEPG = 1600;
static constexpr int kESG = 800;
static constexpr int kF0  = 128;
static constexpr int kH1  = 256;
static constexpr int kH2  = 128;
#define BN_EPS 1e-5f

typedef _Float16 half8 __attribute__((ext_vector_type(8)));
typedef __attribute__((ext_vector_type(4))) float f32x4;

// ================= fp16 MFMA GEMM (big M) =================
// C[M x Nc] = act(A[M x K] @ W[K x Nc]); A fp32 (optionally BN-transformed per
// column k during staging: (a - mean[k]) * rinv[k]), W fp32. Both converted to
// fp16 in registers. BM=128, BN=128, BK=32, 4 waves, each wave 64x64 via 4x4
// frags of mfma_f32_16x16x32_f16. LDS layout [kg][row/col][8]: fragment
// ds_read_b128 conflict-free. B tile loaded via coalesced float4 (not strided
// scalar gather) then scattered to LDS as fp16.
// NOTE: A and C must NOT alias/overlap (cross-block race — r2..r4 failure).
template<int ACT, int TRANS>   // ACT 0=none 1=relu 2=sigmoid
__global__ __launch_bounds__(256)
void gemm_mfma_k(const float* __restrict__ A, const float* __restrict__ W,
                 const float* __restrict__ tr, float* __restrict__ C,
                 int M, int K, int Nc)
{
  __shared__ alignas(16) _Float16 Ash[4096];   // 8 KB
  __shared__ alignas(16) _Float16 Bsh[4096];   // 8 KB
  const int tid = threadIdx.x;
  const int lane = tid & 63;
  const int l15 = lane & 15, lg = lane >> 4;
  const int wave = tid >> 6;
  const int wm = wave >> 1, wn = wave & 1;
  const int bm = blockIdx.x * 128;
  const int bn = blockIdx.y * 128;
  f32x4 acc[4][4];
#pragma unroll
  for (int m = 0; m < 4; ++m)
#pragma unroll
    for (int n = 0; n < 4; ++n) acc[m][n] = (f32x4){0.f, 0.f, 0.f, 0.f};

  for (int k0 = 0; k0 < K; k0 += 32) {
    if (k0) __syncthreads();
    // ---- A tile: 512 (row,kg) slots, 2 per thread
#pragma unroll
    for (int h = 0; h < 2; ++h) {
      int p = tid + h * 256;
      int r = p >> 2, kg = p & 3;
      int kb = k0 + kg * 8;
      float va[8] = {0.f, 0.f, 0.f, 0.f, 0.f, 0.f, 0.f, 0.f};
      if (bm + r < M) {
        const float* s = &A[(size_t)(bm + r) * K + kb];
        float4 u0 = *(const float4*)s, u1 = *(const float4*)(s + 4);
        va[0] = u0.x; va[1] = u0.y; va[2] = u0.z; va[3] = u0.w;
        va[4] = u1.x; va[5] = u1.y; va[6] = u1.z; va[7] = u1.w;
      }
      if (TRANS) {
#pragma unroll
        for (int j = 0; j < 8; ++j) va[j] = (va[j] - tr[kb + j]) * tr[256 + kb + j];
      }
      half8 sa;
#pragma unroll
      for (int j = 0; j < 8; ++j) sa[j] = (_Float16)va[j];
      *(half8*)&Ash[(kg * 128 + r) * 8] = sa;
    }
    // ---- B tile: 32 k x 128 cols as 1024 float4, 4 per thread (coalesced)
#pragma unroll
    for (int l = 0; l < 4; ++l) {
      int q = tid + l * 256;
      int kr = q >> 5;                 // 0..31
      int cq = (q & 31) << 2;          // 0..124
      float4 w4 = *(const float4*)&W[(size_t)(k0 + kr) * Nc + bn + cq];
      int kg = kr >> 3, ke = kr & 7;
      Bsh[(kg * 128 + cq + 0) * 8 + ke] = (_Float16)w4.x;
      Bsh[(kg * 128 + cq + 1) * 8 + ke] = (_Float16)w4.y;
      Bsh[(kg * 128 + cq + 2) * 8 + ke] = (_Float16)w4.z;
      Bsh[(kg * 128 + cq + 3) * 8 + ke] = (_Float16)w4.w;
    }
    __syncthreads();
    half8 aF[4], bF[4];
#pragma unroll
    for (int m = 0; m < 4; ++m)
      aF[m] = *(const half8*)&Ash[(lg * 128 + wm * 64 + m * 16 + l15) * 8];
#pragma unroll
    for (int n = 0; n < 4; ++n)
      bF[n] = *(const half8*)&Bsh[(lg * 128 + wn * 64 + n * 16 + l15) * 8];
#pragma unroll
    for (int m = 0; m < 4; ++m)
#pragma unroll
      for (int n = 0; n < 4; ++n)
        acc[m][n] = __builtin_amdgcn_mfma_f32_16x16x32_f16(aF[m], bF[n], acc[m][n], 0, 0, 0);
  }
  // epilogue: C/D layout col=lane&15, row=(lane>>4)*4+q
#pragma unroll
  for (int m = 0; m < 4; ++m) {
    int row_b = bm + wm * 64 + m * 16 + lg * 4;
#pragma unroll
    for (int q = 0; q < 4; ++q) {
      int row = row_b + q;
      if (row >= M) continue;
#pragma unroll
      for (int n = 0; n < 4; ++n) {
        float v = acc[m][n][q];
        if (ACT == 1) v = fmaxf(v, 0.f);
        else if (ACT == 2) v = 1.f / (1.f + expf(-v));
        C[(size_t)row * Nc + bn + wn * 64 + n * 16 + l15] = v;
      }
    }
  }
}

// ======================= small-M tiled f32 GEMM (M=500 paths) =======================
template<int ACT>  // 0=none 1=relu 2=sigmoid
__global__ __launch_bounds__(256)
void gemm_k(const float* __restrict__ A, const float* __restrict__ W,
            const float* __restrict__ bias, float* __restrict__ C,
            int M, int K, int Nc)
{
  __shared__ float As[32][136];
  __shared__ float Ws[32][68];
  const int tid = threadIdx.x;
  const int bm = blockIdx.x * 128;
  const int bn = blockIdx.y * 64;
  const int tm = (tid & 15) * 8;
  const int tn = (tid >> 4) * 4;
  float acc[8][4];
#pragma unroll
  for (int i = 0; i < 8; ++i)
#pragma unroll
    for (int j = 0; j < 4; ++j) acc[i][j] = 0.f;

  for (int k0 = 0; k0 < K; k0 += 32) {
#pragma unroll
    for (int l = 0; l < 4; ++l) {
      int idx = tid + l * 256;
      int r = idx >> 3;
      int kq = (idx & 7) << 2;
      int gr = bm + r;
      float4 v = make_float4(0.f, 0.f, 0.f, 0.f);
      if (gr < M) v = *(const float4*)&A[(size_t)gr * K + k0 + kq];
      As[kq + 0][r] = v.x; As[kq + 1][r] = v.y;
      As[kq + 2][r] = v.z; As[kq + 3][r] = v.w;
    }
#pragma unroll
    for (int l = 0; l < 2; ++l) {
      int idx = tid + l * 256;
      int r = idx >> 4;
      int nq = (idx & 15) << 2;
      *(float4*)&Ws[r][nq] = *(const float4*)&W[(size_t)(k0 + r) * Nc + bn + nq];
    }
    __syncthreads();
#pragma unroll
    for (int kk = 0; kk < 32; ++kk) {
      float4 a0 = *(float4*)&As[kk][tm];
      float4 a1 = *(float4*)&As[kk][tm + 4];
      float4 w4 = *(float4*)&Ws[kk][tn];
      float am[8] = {a0.x, a0.y, a0.z, a0.w, a1.x, a1.y, a1.z, a1.w};
      float wn4[4] = {w4.x, w4.y, w4.z, w4.w};
#pragma unroll
      for (int i = 0; i < 8; ++i)
#pragma unroll
        for (int j = 0; j < 4; ++j) acc[i][j] += am[i] * wn4[j];
    }
    __syncthreads();
  }
  float4 bv = make_float4(0.f, 0.f, 0.f, 0.f);
  if (bias) bv = *(const float4*)&bias[bn + tn];
#pragma unroll
  for (int i = 0; i < 8; ++i) {
    int row = bm + tm + i;
    if (row >= M) break;
    float o0 = acc[i][0] + bv.x, o1 = acc[i][1] + bv.y;
    float o2 = acc[i][2] + bv.z, o3 = acc[i][3] + bv.w;
    if (ACT == 1) {
      o0 = fmaxf(o0, 0.f); o1 = fmaxf(o1, 0.f);
      o2 = fmaxf(o2, 0.f); o3 = fmaxf(o3, 0.f);
    } else if (ACT == 2) {
      o0 = 1.f / (1.f + expf(-o0)); o1 = 1.f / (1.f + expf(-o1));
      o2 = 1.f / (1.f + expf(-o2)); o3 = 1.f / (1.f + expf(-o3));
    }
    *(float4*)&C[(size_t)row * Nc + bn + tn] = make_float4(o0, o1, o2, o3);
  }
}

// ======================= per-graph GCN aggregation (fused tails) =======================
// OUT = tail( act( A_norm @ H + bias ) ) per graph. A built dense in LDS
// (41.6 KB only — H is read directly from global; its 100-row slice is
// L1/L2-resident, so staging it in LDS was pure occupancy loss).
// SEGBN: fused per-graph batchnorm (after ACT). L2N: fused row l2-normalize.
// POOL: fused mean-pool -> OUT is [B][W] instead of per-node rows.
// Deterministic: At atomics add identical values per cell; all reductions
// fixed-order or lane-shuffle.
template<int W, int ACT, int SEGBN, int L2N, int POOL>
__global__ __launch_bounds__(512)
void gcn_agg_k(const float* __restrict__ H, const int* __restrict__ srcI,
               const int* __restrict__ dstI, const float* __restrict__ bias,
               float* __restrict__ OUT, int epg)
{
  extern __shared__ __align__(16) float lds[];
  float* At = lds;               // [100][104] transposed At[s][d]; reused as scratch later
  __shared__ int scnt[kNPG];
  __shared__ float sdinv[kNPG];
  const int g = blockIdx.x, tid = threadIdx.x;
  const int base = g * kNPG;
  const size_t ebase = (size_t)g * epg;

  for (int i = tid; i < 100 * 104; i += 512) At[i] = 0.f;
  if (tid < kNPG) scnt[tid] = 0;
  __syncthreads();
  for (int e = tid; e < epg; e += 512) atomicAdd(&scnt[dstI[ebase + e] - base], 1);
  __syncthreads();
  if (tid < kNPG) sdinv[tid] = rsqrtf((float)scnt[tid] + 1.f);
  __syncthreads();
  for (int e = tid; e < epg; e += 512) {
    int s = srcI[ebase + e] - base;
    int d = dstI[ebase + e] - base;
    atomicAdd(&At[s * 104 + d], sdinv[s] * sdinv[d]);
  }
  __syncthreads();
  if (tid < kNPG) At[tid * 104 + tid] += sdinv[tid] * sdinv[tid];
  __syncthreads();

  constexpr int CG = W / 4;          // 64 (W=256) or 32 (W=128)
  constexpr int IG = 512 / CG;       // 8 or 16
  constexpr int NB = (IG == 8) ? 2 : 1;   // row passes: IG*NB*8 = 128 >= 100
  const int cg = tid % CG, ig = tid / CG;
  const int c0 = cg * 4;
  float4 bv = make_float4(0.f, 0.f, 0.f, 0.f);
  if (bias) bv = *(const float4*)&bias[c0];

  float acc[NB][8][4];
#pragma unroll
  for (int ib = 0; ib < NB; ++ib)
#pragma unroll
    for (int i = 0; i < 8; ++i)
#pragma unroll
      for (int j = 0; j < 4; ++j) acc[ib][i][j] = 0.f;

  const float* Hg = H + (size_t)base * W + c0;
#pragma unroll 2
  for (int j = 0; j < 100; ++j) {
    float4 h4 = *(const float4*)&Hg[(size_t)j * W];
    float hn[4] = {h4.x, h4.y, h4.z, h4.w};
#pragma unroll
    for (int ib = 0; ib < NB; ++ib) {
      int i0 = (ig + ib * IG) * 8;
      float4 a0 = *(float4*)&At[j * 104 + i0];       // wave-broadcast
      float4 a1 = *(float4*)&At[j * 104 + i0 + 4];
      float am[8] = {a0.x, a0.y, a0.z, a0.w, a1.x, a1.y, a1.z, a1.w};
#pragma unroll
      for (int ii = 0; ii < 8; ++ii)
#pragma unroll
        for (int jj = 0; jj < 4; ++jj) acc[ib][ii][jj] += am[ii] * hn[jj];
    }
  }
  // bias + activation
#pragma unroll
  for (int ib = 0; ib < NB; ++ib)
#pragma unroll
    for (int ii = 0; ii < 8; ++ii) {
      float b4[4] = {bv.x, bv.y, bv.z, bv.w};
#pragma unroll
      for (int jj = 0; jj < 4; ++jj) {
        float v = acc[ib][ii][jj] + b4[jj];
        if (ACT == 1) v = fmaxf(v, 0.f);
        acc[ib][ii][jj] = v;
      }
    }

  if constexpr (SEGBN) {
    // per-column stats over the graph's 100 rows (fixed-order, deterministic)
    float ps[4] = {0.f, 0.f, 0.f, 0.f}, ps2[4] = {0.f, 0.f, 0.f, 0.f};
#pragma unroll
    for (int ib = 0; ib < NB; ++ib)
#pragma unroll
      for (int ii = 0; ii < 8; ++ii) {
        int i = (ig + ib * IG) * 8 + ii;
        if (i < 100)
#pragma unroll
          for (int jj = 0; jj < 4; ++jj) {
            float v = acc[ib][ii][jj];
            ps[jj] += v; ps2[jj] += v * v;
          }
      }
    __syncthreads();                       // At dead -> reuse as scratch
    float* ssum = At;                      // [IG][W]
    float* ssq  = At + IG * W;             // [IG][W]
    *(float4*)&ssum[ig * W + c0] = make_float4(ps[0], ps[1], ps[2], ps[3]);
    *(float4*)&ssq[ig * W + c0]  = make_float4(ps2[0], ps2[1], ps2[2], ps2[3]);
    __syncthreads();
    float mm[4], ri[4];
#pragma unroll
    for (int jj = 0; jj < 4; ++jj) {
      float s = 0.f, s2 = 0.f;
      for (int q = 0; q < IG; ++q) { s += ssum[q * W + c0 + jj]; s2 += ssq[q * W + c0 + jj]; }
      mm[jj] = s / 100.f;
      ri[jj] = rsqrtf(s2 / 100.f - mm[jj] * mm[jj] + BN_EPS);
    }
#pragma unroll
    for (int ib = 0; ib < NB; ++ib)
#pragma unroll
      for (int ii = 0; ii < 8; ++ii)
#pragma unroll
        for (int jj = 0; jj < 4; ++jj)
          acc[ib][ii][jj] = (acc[ib][ii][jj] - mm[jj]) * ri[jj];
  }

  if constexpr (L2N) {   // W == 128 only: row owned by 32 consecutive lanes
#pragma unroll
    for (int ii = 0; ii < 8; ++ii) {
      float ss = acc[0][ii][0] * acc[0][ii][0] + acc[0][ii][1] * acc[0][ii][1]
               + acc[0][ii][2] * acc[0][ii][2] + acc[0][ii][3] * acc[0][ii][3];
#pragma unroll
      for (int o = 1; o <= 16; o <<= 1) ss += __shfl_xor(ss, o, 64);
      float inv = 1.f / fmaxf(sqrtf(ss), 1e-12f);
#pragma unroll
      for (int jj = 0; jj < 4; ++jj) acc[0][ii][jj] *= inv;
    }
  }

  if constexpr (POOL) {  // W == 128: mean over the 100 rows -> OUT[g][W]
    float ps[4] = {0.f, 0.f, 0.f, 0.f};
#pragma unroll
    for (int ii = 0; ii < 8; ++ii) {
      int i = ig * 8 + ii;
      if (i < 100)
#pragma unroll
        for (int jj = 0; jj < 4; ++jj) ps[jj] += acc[0][ii][jj];
    }
    __syncthreads();                       // At dead -> reuse as scratch
    float* sp = At;                        // [IG][W] = 16 x 128
    *(float4*)&sp[ig * W + c0] = make_float4(ps[0], ps[1], ps[2], ps[3]);
    __syncthreads();
    if (tid < CG) {
      float s[4] = {0.f, 0.f, 0.f, 0.f};
      for (int q = 0; q < IG; ++q)
#pragma unroll
        for (int jj = 0; jj < 4; ++jj) s[jj] += sp[q * W + tid * 4 + jj];
      *(float4*)&OUT[(size_t)g * W + tid * 4] =
          make_float4(s[0] / 100.f, s[1] / 100.f, s[2] / 100.f, s[3] / 100.f);
    }
  } else {
#pragma unroll
    for (int ib = 0; ib < NB; ++ib)
#pragma unroll
      for (int ii = 0; ii < 8; ++ii) {
        int i = (ig + ib * IG) * 8 + ii;
        if (i < 100)
          *(float4*)&OUT[(size_t)(base + i) * W + c0] =
              make_float4(acc[ib][ii][0], acc[ib][ii][1], acc[ib][ii][2], acc[ib][ii][3]);
      }
  }
}

// ============ deterministic BatchNorm stats (50000 x 256), 2-stage ============
__global__ __launch_bounds__(256)
void bn_part_k(const float* __restrict__ X, float* __restrict__ P)
{
  const int b = blockIdx.x, c = threadIdx.x;
  const float* xb = X + (size_t)b * 250 * kH1;
  float s = 0.f, s2 = 0.f;
  for (int r = 0; r < 250; ++r) {
    float v = xb[(size_t)r * kH1 + c];
    s += v; s2 += v * v;
  }
  P[b * 512 + c] = s;
  P[b * 512 + 256 + c] = s2;
}
__global__ __launch_bounds__(256)
void bn_red_k(const float* __restrict__ P, float* __restrict__ stats)
{
  const int c = threadIdx.x;
  float s = 0.f, s2 = 0.f;
  for (int b = 0; b < 200; ++b) {
    s  += P[b * 512 + c];
    s2 += P[b * 512 + 256 + c];
  }
  float m = s / (float)kN;
  float v = s2 / (float)kN - m * m;
  stats[512 + c] = m;
  stats[768 + c] = rsqrtf(v + BN_EPS);
}

// column-parallel BN, in place: X[rows][cols], one block (64 thr) per column
__global__ __launch_bounds__(64)
void bn_cols_k(float* __restrict__ X, int rows, int cols)
{
  const int c = blockIdx.x, t = threadIdx.x;
  float s = 0.f, s2 = 0.f;
  for (int r = t; r < rows; r += 64) {
    float v = X[(size_t)r * cols + c];
    s += v; s2 += v * v;
  }
#pragma unroll
  for (int o = 32; o; o >>= 1) { s += __shfl_xor(s, o, 64); s2 += __shfl_xor(s2, o, 64); }
  float m = s / (float)rows;
  float var = s2 / (float)rows - m * m;
  float rinv = rsqrtf(var + BN_EPS);
  for (int r = t; r < rows; r += 64)
    X[(size_t)r * cols + c] = (X[(size_t)r * cols + c] - m) * rinv;
}

// row-wise L2 normalize (128 cols) — target path only now
__global__ __launch_bounds__(256)
void l2n_k(const float* __restrict__ X, float* __restrict__ Y, int rows)
{
  const int w = threadIdx.x >> 6, lane = threadIdx.x & 63;
  const int row = blockIdx.x * 4 + w;
  if (row >= rows) return;
  float2 v = *(const float2*)&X[(size_t)row * kH2 + lane * 2];
  float ss = v.x * v.x + v.y * v.y;
#pragma unroll
  for (int o = 32; o; o >>= 1) ss += __shfl_xor(ss, o, 64);
  float inv = 1.f / fmaxf(sqrtf(ss), 1e-12f);
  *(float2*)&Y[(size_t)row * kH2 + lane * 2] = make_float2(v.x * inv, v.y * inv);
}

__global__ __launch_bounds__(128)
void seg_max_k(const float* __restrict__ Z, const float* __restrict__ NOI,
               float* __restrict__ ZG, float* __restrict__ ZPG)
{
  const int g = blockIdx.x, c = threadIdx.x;
  const size_t b = (size_t)g * kNPG * kH2;
  float m1 = -INFINITY, m2 = -INFINITY;
  for (int r = 0; r < kNPG; ++r) {
    float v = Z[b + r * kH2 + c];
    float n = NOI[b + r * kH2 + c];
    m1 = fmaxf(m1, v);
    m2 = fmaxf(m2, v + n);
  }
  ZG[g * kH2 + c] = m1;
  ZPG[g * kH2 + c] = m2;
}

// =========================================================================
extern "C" void kernel_launch(void* const* d_in, const int* in_sizes, int n_in,
                              void* d_out, int out_size, void* d_ws, size_t ws_size,
                              hipStream_t stream)
{
  const float* x        = (const float*)d_in[0];
  const int*   srcI     = (const int*)d_in[1];
  const int*   dstI     = (const int*)d_in[2];
  const float* pos_x    = (const float*)d_in[4];
  const int*   psrc     = (const int*)d_in[5];
  const int*   pdst     = (const int*)d_in[6];
  const float* neg_x    = (const float*)d_in[8];
  const int*   nsrc     = (const int*)d_in[9];
  const int*   ndst     = (const int*)d_in[10];
  const float* target_x = (const float*)d_in[12];
  const float* noise    = (const float*)d_in[13];
  const float* W_enc1   = (const float*)d_in[14];
  const float* b_enc1   = (const float*)d_in[15];
  const float* W_enc2   = (const float*)d_in[16];
  const float* b_enc2   = (const float*)d_in[17];
  const float* W_dec1   = (const float*)d_in[18];
  const float* W_dec2   = (const float*)d_in[19];
  const float* Wn1      = (const float*)d_in[20];
  const float* bn1      = (const float*)d_in[21];
  const float* Wn2      = (const float*)d_in[22];
  const float* bn2      = (const float*)d_in[23];
  const float* Ws1      = (const float*)d_in[24];
  const float* bs1      = (const float*)d_in[25];
  const float* Wp1      = (const float*)d_in[26];
  const float* bp1      = (const float*)d_in[27];
  const float* Wp2      = (const float*)d_in[28];
  const float* bp2      = (const float*)d_in[29];

  float* out  = (float*)d_out;
  float* o_z   = out;                 // N x 128
  float* o_zg  = out + 6400000;       // 500 x 128
  float* o_xr  = out + 6464000;       // N x 128
  float* o_pos = out + 12864000;      // 500 x 128
  float* o_neg = out + 12928000;
  float* o_zgm = out + 12992000;
  float* o_zpm = out + 13056000;
  float* o_tz  = out + 13120000;

  // WORKSPACE MAP. bufB as N x 256 spans [12800000, 25600000). bufC is no
  // longer used (pos/neg tails fused). Rule: a kernel reading a buffer must
  // never write an overlapping one (r2-r4 race lesson).
  float* ws    = (float*)d_ws;
  float* bufA  = ws;                  // N x 256 (lower N x 128 also used)
  float* bufB  = ws + 12800000;       // N x 256
  float* stats = ws + 25600000;       // 1024 floats: [512..768)=mean [768..1024)=rinv
  float* t500  = ws + 25601024;       // 500 x 128
  float* t1    = t500 + 64000;        // 500 x 256
  float* t2    = t1 + 128000;         // 500 x 128
  float* zpg   = t2 + 64000;          // 500 x 128
  float* pstat = bufA;                // 200*512 floats; bufA dead there, consumed
                                      // by bn_red before bufA's next write
  if (ws_size < (size_t)(25921024) * sizeof(float)) return;

  constexpr unsigned kAggLds = 100 * 104 * 4;   // 41.6 KB -> 3 blocks/CU

  const dim3 gB(391, 2);   // M=50000, Nc=256
  const dim3 gC(391, 1);   // M=50000, Nc=128
  auto gg = [](int M, int Nc) {
    return dim3((unsigned)((M + 127) / 128), (unsigned)(Nc / 64), 1);
  };

  // ---------------- main encode ----------------
  gemm_mfma_k<0, 0><<<gB, 256, 0, stream>>>(x, W_enc1, nullptr, bufA, kN, kF0, kH1);
  gcn_agg_k<256, 1, 0, 0, 0><<<kB, 512, kAggLds, stream>>>(bufA, srcI, dstI, b_enc1, bufB, kEPG);
  bn_part_k<<<200, 256, 0, stream>>>(bufB, pstat);
  bn_red_k<<<1, 256, 0, stream>>>(pstat, stats);
  gemm_mfma_k<0, 1><<<gC, 256, 0, stream>>>(bufB, W_enc2, stats + 512, bufA, kN, kH1, kH2);
  gcn_agg_k<128, 0, 0, 1, 0><<<kB, 512, kAggLds, stream>>>(bufA, srcI, dstI, b_enc2, o_z, kEPG);
  // decode
  gemm_mfma_k<1, 0><<<gB, 256, 0, stream>>>(o_z, W_dec1, nullptr, bufA, kN, kH2, kH1);
  gemm_mfma_k<2, 0><<<gC, 256, 0, stream>>>(bufA, W_dec2, nullptr, o_xr, kN, kH1, kF0);
  // pooling + projection heads
  seg_max_k<<<kB, 128, 0, stream>>>(o_z, noise, o_zg, zpg);
  gemm_k<1><<<gg(kB, kH2), 256, 0, stream>>>(o_zg, Wp1, bp1, t500, kB, kH2, kH2);
  gemm_k<0><<<gg(kB, kH2), 256, 0, stream>>>(t500, Wp2, bp2, o_zgm, kB, kH2, kH2);
  gemm_k<1><<<gg(kB, kH2), 256, 0, stream>>>(zpg, Wp1, bp1, t500, kB, kH2, kH2);
  gemm_k<0><<<gg(kB, kH2), 256, 0, stream>>>(t500, Wp2, bp2, o_zpm, kB, kH2, kH2);

  // ---------------- positive subgraphs ----------------
  gemm_mfma_k<0, 0><<<gB, 256, 0, stream>>>(pos_x, Ws1, nullptr, bufA, kN, kF0, kH1);
  gcn_agg_k<256, 1, 1, 0, 0><<<kB, 512, kAggLds, stream>>>(bufA, psrc, pdst, bs1, bufB, kESG);
  gemm_mfma_k<0, 0><<<gC, 256, 0, stream>>>(bufB, W_enc2, nullptr, bufA, kN, kH1, kH2);
  gcn_agg_k<128, 0, 0, 1, 1><<<kB, 512, kAggLds, stream>>>(bufA, psrc, pdst, b_enc2, o_pos, kESG);

  // ---------------- negative subgraphs ----------------
  gemm_mfma_k<0, 0><<<gB, 256, 0, stream>>>(neg_x, Ws1, nullptr, bufA, kN, kF0, kH1);
  gcn_agg_k<256, 1, 1, 0, 0><<<kB, 512, kAggLds, stream>>>(bufA, nsrc, ndst, bs1, bufB, kESG);
  gemm_mfma_k<0, 0><<<gC, 256, 0, stream>>>(bufB, W_enc2, nullptr, bufA, kN, kH1, kH2);
  gcn_agg_k<128, 0, 0, 1, 1><<<kB, 512, kAggLds, stream>>>(bufA, nsrc, ndst, b_enc2, o_neg, kESG);

  // ---------------- target node encoder ----------------
  gemm_k<1><<<gg(kB, kH1), 256, 0, stream>>>(target_x, Wn1, bn1, t1, kB, kF0, kH1);
  bn_cols_k<<<256, 64, 0, stream>>>(t1, kB, kH1);
  gemm_k<0><<<gg(kB, kH2), 256, 0, stream>>>(t1, Wn2, bn2, t2, kB, kH1, kH2);
  l2n_k<<<125, 256, 0, stream>>>(t2, o_tz, kB);

  (void)in_sizes; (void)n_in; (void)out_size;
}

// Round 7
// 487.195 us; speedup vs baseline: 2.4355x; 1.2337x over previous
//
#include <hip/hip_runtime.h>
#include <math.h>

static constexpr int kN   = 50000;
static constexpr int kB   = 500;
static constexpr int kNPG = 100;
static constexpr int kEPG = 1600;
static constexpr int kESG = 800;
static constexpr int kF0  = 128;
static constexpr int kH1  = 256;
static constexpr int kH2  = 128;
#define BN_EPS 1e-5f

typedef _Float16 half8 __attribute__((ext_vector_type(8)));
typedef __attribute__((ext_vector_type(4))) float f32x4;

static constexpr int kAdS = 132;                    // Ad row stride in floats
static constexpr unsigned kAggLds = 112u * 132u * 4u;  // 59136 B dynamic LDS

// ================= fp16 MFMA GEMM (big M) =================
// C = act(A @ W). AT: float (optionally BN-transform via tr) or _Float16.
// OT: float or _Float16. BM=128,BN=128,BK=32, 4 waves, 4x4 frags of
// mfma_f32_16x16x32_f16. LDS [kg][row/col][8], frag ds_read_b128 conflict-free.
// NOTE: A and C must NOT alias (cross-block race — r2..r4 lesson).
template<int ACT, int TRANS, typename AT, typename OT>  // ACT 0=none 1=relu 2=sigmoid
__global__ __launch_bounds__(256)
void gemm_mfma_k(const AT* __restrict__ A, const float* __restrict__ W,
                 const float* __restrict__ tr, OT* __restrict__ C,
                 int M, int K, int Nc)
{
  __shared__ alignas(16) _Float16 Ash[4096];
  __shared__ alignas(16) _Float16 Bsh[4096];
  const int tid = threadIdx.x;
  const int lane = tid & 63;
  const int l15 = lane & 15, lg = lane >> 4;
  const int wave = tid >> 6;
  const int wm = wave >> 1, wn = wave & 1;
  const int bm = blockIdx.x * 128;
  const int bn = blockIdx.y * 128;
  f32x4 acc[4][4];
#pragma unroll
  for (int m = 0; m < 4; ++m)
#pragma unroll
    for (int n = 0; n < 4; ++n) acc[m][n] = (f32x4){0.f, 0.f, 0.f, 0.f};

  for (int k0 = 0; k0 < K; k0 += 32) {
    if (k0) __syncthreads();
    // ---- A tile: 512 (row,kg) slots, 2 per thread
#pragma unroll
    for (int h = 0; h < 2; ++h) {
      int p = tid + h * 256;
      int r = p >> 2, kg = p & 3;
      int kb = k0 + kg * 8;
      half8 sa;
#pragma unroll
      for (int j = 0; j < 8; ++j) sa[j] = (_Float16)0.f;
      if (bm + r < M) {
        if constexpr (sizeof(AT) == 4) {
          const float* s = (const float*)A + (size_t)(bm + r) * K + kb;
          float4 u0 = *(const float4*)s, u1 = *(const float4*)(s + 4);
          float va[8] = {u0.x, u0.y, u0.z, u0.w, u1.x, u1.y, u1.z, u1.w};
          if constexpr (TRANS) {
#pragma unroll
            for (int j = 0; j < 8; ++j) va[j] = (va[j] - tr[kb + j]) * tr[256 + kb + j];
          }
#pragma unroll
          for (int j = 0; j < 8; ++j) sa[j] = (_Float16)va[j];
        } else {
          sa = *(const half8*)((const _Float16*)A + (size_t)(bm + r) * K + kb);
        }
      }
      *(half8*)&Ash[(kg * 128 + r) * 8] = sa;
    }
    // ---- B tile: 32 k x 128 cols, coalesced float4, scatter to LDS fp16
#pragma unroll
    for (int l = 0; l < 4; ++l) {
      int q = tid + l * 256;
      int kr = q >> 5;
      int cq = (q & 31) << 2;
      float4 w4 = *(const float4*)&W[(size_t)(k0 + kr) * Nc + bn + cq];
      int kg = kr >> 3, ke = kr & 7;
      Bsh[(kg * 128 + cq + 0) * 8 + ke] = (_Float16)w4.x;
      Bsh[(kg * 128 + cq + 1) * 8 + ke] = (_Float16)w4.y;
      Bsh[(kg * 128 + cq + 2) * 8 + ke] = (_Float16)w4.z;
      Bsh[(kg * 128 + cq + 3) * 8 + ke] = (_Float16)w4.w;
    }
    __syncthreads();
    half8 aF[4], bF[4];
#pragma unroll
    for (int m = 0; m < 4; ++m)
      aF[m] = *(const half8*)&Ash[(lg * 128 + wm * 64 + m * 16 + l15) * 8];
#pragma unroll
    for (int n = 0; n < 4; ++n)
      bF[n] = *(const half8*)&Bsh[(lg * 128 + wn * 64 + n * 16 + l15) * 8];
#pragma unroll
    for (int m = 0; m < 4; ++m)
#pragma unroll
      for (int n = 0; n < 4; ++n)
        acc[m][n] = __builtin_amdgcn_mfma_f32_16x16x32_f16(aF[m], bF[n], acc[m][n], 0, 0, 0);
  }
  // epilogue: C/D layout col=lane&15, row=(lane>>4)*4+q
#pragma unroll
  for (int m = 0; m < 4; ++m) {
    int row_b = bm + wm * 64 + m * 16 + lg * 4;
#pragma unroll
    for (int q = 0; q < 4; ++q) {
      int row = row_b + q;
      if (row >= M) continue;
#pragma unroll
      for (int n = 0; n < 4; ++n) {
        float v = acc[m][n][q];
        if (ACT == 1) v = fmaxf(v, 0.f);
        else if (ACT == 2) v = 1.f / (1.f + expf(-v));
        C[(size_t)row * Nc + bn + wn * 64 + n * 16 + l15] = (OT)v;
      }
    }
  }
}

// ======================= small-M tiled f32 GEMM (M=500 paths) =======================
template<int ACT>
__global__ __launch_bounds__(256)
void gemm_k(const float* __restrict__ A, const float* __restrict__ W,
            const float* __restrict__ bias, float* __restrict__ C,
            int M, int K, int Nc)
{
  __shared__ float As[32][136];
  __shared__ float Ws[32][68];
  const int tid = threadIdx.x;
  const int bm = blockIdx.x * 128;
  const int bn = blockIdx.y * 64;
  const int tm = (tid & 15) * 8;
  const int tn = (tid >> 4) * 4;
  float acc[8][4];
#pragma unroll
  for (int i = 0; i < 8; ++i)
#pragma unroll
    for (int j = 0; j < 4; ++j) acc[i][j] = 0.f;

  for (int k0 = 0; k0 < K; k0 += 32) {
#pragma unroll
    for (int l = 0; l < 4; ++l) {
      int idx = tid + l * 256;
      int r = idx >> 3;
      int kq = (idx & 7) << 2;
      int gr = bm + r;
      float4 v = make_float4(0.f, 0.f, 0.f, 0.f);
      if (gr < M) v = *(const float4*)&A[(size_t)gr * K + k0 + kq];
      As[kq + 0][r] = v.x; As[kq + 1][r] = v.y;
      As[kq + 2][r] = v.z; As[kq + 3][r] = v.w;
    }
#pragma unroll
    for (int l = 0; l < 2; ++l) {
      int idx = tid + l * 256;
      int r = idx >> 4;
      int nq = (idx & 15) << 2;
      *(float4*)&Ws[r][nq] = *(const float4*)&W[(size_t)(k0 + r) * Nc + bn + nq];
    }
    __syncthreads();
#pragma unroll
    for (int kk = 0; kk < 32; ++kk) {
      float4 a0 = *(float4*)&As[kk][tm];
      float4 a1 = *(float4*)&As[kk][tm + 4];
      float4 w4 = *(float4*)&Ws[kk][tn];
      float am[8] = {a0.x, a0.y, a0.z, a0.w, a1.x, a1.y, a1.z, a1.w};
      float wn4[4] = {w4.x, w4.y, w4.z, w4.w};
#pragma unroll
      for (int i = 0; i < 8; ++i)
#pragma unroll
        for (int j = 0; j < 4; ++j) acc[i][j] += am[i] * wn4[j];
    }
    __syncthreads();
  }
  float4 bv = make_float4(0.f, 0.f, 0.f, 0.f);
  if (bias) bv = *(const float4*)&bias[bn + tn];
#pragma unroll
  for (int i = 0; i < 8; ++i) {
    int row = bm + tm + i;
    if (row >= M) break;
    float o0 = acc[i][0] + bv.x, o1 = acc[i][1] + bv.y;
    float o2 = acc[i][2] + bv.z, o3 = acc[i][3] + bv.w;
    if (ACT == 1) {
      o0 = fmaxf(o0, 0.f); o1 = fmaxf(o1, 0.f);
      o2 = fmaxf(o2, 0.f); o3 = fmaxf(o3, 0.f);
    } else if (ACT == 2) {
      o0 = 1.f / (1.f + expf(-o0)); o1 = 1.f / (1.f + expf(-o1));
      o2 = 1.f / (1.f + expf(-o2)); o3 = 1.f / (1.f + expf(-o3));
    }
    *(float4*)&C[(size_t)row * Nc + bn + tn] = make_float4(o0, o1, o2, o3);
  }
}

// ================= per-graph GCN aggregation, MFMA (fused tails) =================
// OUT = tail( act( A_norm @ H + bias ) ) per graph. A built dense in LDS as
// Ad[d][s] (112 x 132 f32, zero-padded to K=128 / M=112 so MFMA tails are
// exact zeros). Matmul on matrix cores: A-frags = 2x ds_read_b128 + cvt fp16,
// B-frags = 8 scalar H loads (graph slice is L2-hot). 4 K-steps of
// mfma_f32_16x16x32_f16. Deterministic (identical-value LDS atomics,
// fixed-order shuffles).
template<int W, int ACT, int SEGBN, int L2N, int POOL, typename HT, typename OT>
__global__ __launch_bounds__(512, 4)
void gcn_agg_k(const HT* __restrict__ H, const int* __restrict__ srcI,
               const int* __restrict__ dstI, const float* __restrict__ bias,
               OT* __restrict__ OUT, int epg)
{
  extern __shared__ __align__(16) float lds[];
  float* Ad = lds;                      // [112][132]: Ad[d][s] = A[d][s]
  __shared__ int scnt[kNPG];
  __shared__ float sdinv[kNPG];
  const int g = blockIdx.x, tid = threadIdx.x;
  const int base = g * kNPG;
  const size_t ebase = (size_t)g * epg;
  const int lane = tid & 63, wv = tid >> 6;
  const int l15 = lane & 15, lg = lane >> 4;

  for (int i = tid; i < 112 * kAdS; i += 512) Ad[i] = 0.f;
  if (tid < kNPG) scnt[tid] = 0;
  __syncthreads();
  for (int e = tid; e < epg; e += 512) atomicAdd(&scnt[dstI[ebase + e] - base], 1);
  __syncthreads();
  if (tid < kNPG) sdinv[tid] = rsqrtf((float)scnt[tid] + 1.f);
  __syncthreads();
  for (int e = tid; e < epg; e += 512) {
    int s = srcI[ebase + e] - base;
    int d = dstI[ebase + e] - base;
    atomicAdd(&Ad[d * kAdS + s], sdinv[s] * sdinv[d]);
  }
  __syncthreads();
  if (tid < kNPG) Ad[tid * kAdS + tid] += sdinv[tid] * sdinv[tid];
  __syncthreads();

  if constexpr (W == 256) {
    // wave wv owns cols [wv*32, wv*32+32), all 7 m-tiles (rows 0..111)
    const int cbase = wv * 32;
    f32x4 acc[7][2];
#pragma unroll
    for (int mt = 0; mt < 7; ++mt) {
      acc[mt][0] = (f32x4){0.f, 0.f, 0.f, 0.f};
      acc[mt][1] = (f32x4){0.f, 0.f, 0.f, 0.f};
    }
#pragma unroll
    for (int k0 = 0; k0 < 128; k0 += 32) {
      half8 bF[2];
#pragma unroll
      for (int t = 0; t < 2; ++t) {
        int col = cbase + t * 16 + l15;
#pragma unroll
        for (int e = 0; e < 8; ++e) {
          int row = min(base + k0 + lg * 8 + e, kN - 1);   // clamp: A=0 past 100
          bF[t][e] = (_Float16)H[(size_t)row * W + col];
        }
      }
#pragma unroll
      for (int mt = 0; mt < 7; ++mt) {
        const float* ap = &Ad[(mt * 16 + l15) * kAdS + k0 + lg * 8];
        f32x4 a0 = *(const f32x4*)ap;
        f32x4 a1 = *(const f32x4*)(ap + 4);
        half8 aF;
#pragma unroll
        for (int j = 0; j < 4; ++j) { aF[j] = (_Float16)a0[j]; aF[4 + j] = (_Float16)a1[j]; }
        acc[mt][0] = __builtin_amdgcn_mfma_f32_16x16x32_f16(aF, bF[0], acc[mt][0], 0, 0, 0);
        acc[mt][1] = __builtin_amdgcn_mfma_f32_16x16x32_f16(aF, bF[1], acc[mt][1], 0, 0, 0);
      }
    }
    float bv0 = bias ? bias[cbase + l15] : 0.f;
    float bv1 = bias ? bias[cbase + 16 + l15] : 0.f;
#pragma unroll
    for (int mt = 0; mt < 7; ++mt)
#pragma unroll
      for (int q = 0; q < 4; ++q) {
        float v0 = acc[mt][0][q] + bv0, v1 = acc[mt][1][q] + bv1;
        if (ACT == 1) { v0 = fmaxf(v0, 0.f); v1 = fmaxf(v1, 0.f); }
        acc[mt][0][q] = v0; acc[mt][1][q] = v1;
      }
    if constexpr (SEGBN) {
      float s0 = 0.f, s20 = 0.f, s1 = 0.f, s21 = 0.f;
#pragma unroll
      for (int mt = 0; mt < 7; ++mt)
#pragma unroll
        for (int q = 0; q < 4; ++q) {
          int row = mt * 16 + lg * 4 + q;
          if (row < 100) {
            float v0 = acc[mt][0][q], v1 = acc[mt][1][q];
            s0 += v0; s20 += v0 * v0; s1 += v1; s21 += v1 * v1;
          }
        }
      s0 += __shfl_xor(s0, 16, 64);  s0 += __shfl_xor(s0, 32, 64);
      s20 += __shfl_xor(s20, 16, 64); s20 += __shfl_xor(s20, 32, 64);
      s1 += __shfl_xor(s1, 16, 64);  s1 += __shfl_xor(s1, 32, 64);
      s21 += __shfl_xor(s21, 16, 64); s21 += __shfl_xor(s21, 32, 64);
      float m0 = s0 / 100.f, r0 = rsqrtf(s20 / 100.f - m0 * m0 + BN_EPS);
      float m1 = s1 / 100.f, r1 = rsqrtf(s21 / 100.f - m1 * m1 + BN_EPS);
#pragma unroll
      for (int mt = 0; mt < 7; ++mt)
#pragma unroll
        for (int q = 0; q < 4; ++q) {
          acc[mt][0][q] = (acc[mt][0][q] - m0) * r0;
          acc[mt][1][q] = (acc[mt][1][q] - m1) * r1;
        }
    }
#pragma unroll
    for (int mt = 0; mt < 7; ++mt)
#pragma unroll
      for (int q = 0; q < 4; ++q) {
        int row = mt * 16 + lg * 4 + q;
        if (row < 100) {
          OUT[(size_t)(base + row) * W + cbase + l15] = (OT)acc[mt][0][q];
          OUT[(size_t)(base + row) * W + cbase + 16 + l15] = (OT)acc[mt][1][q];
        }
      }
  } else {
    // W == 128: wave wv owns m-tile wv (waves 0..6), all 8 n-tiles
    const int mt = wv;
    f32x4 acc[8];
#pragma unroll
    for (int nt = 0; nt < 8; ++nt) acc[nt] = (f32x4){0.f, 0.f, 0.f, 0.f};
    if (mt < 7) {
#pragma unroll
      for (int k0 = 0; k0 < 128; k0 += 32) {
        const float* ap = &Ad[(mt * 16 + l15) * kAdS + k0 + lg * 8];
        f32x4 a0 = *(const f32x4*)ap;
        f32x4 a1 = *(const f32x4*)(ap + 4);
        half8 aF;
#pragma unroll
        for (int j = 0; j < 4; ++j) { aF[j] = (_Float16)a0[j]; aF[4 + j] = (_Float16)a1[j]; }
#pragma unroll
        for (int nt = 0; nt < 8; ++nt) {
          half8 bF;
#pragma unroll
          for (int e = 0; e < 8; ++e) {
            int row = min(base + k0 + lg * 8 + e, kN - 1);
            bF[e] = (_Float16)H[(size_t)row * W + nt * 16 + l15];
          }
          acc[nt] = __builtin_amdgcn_mfma_f32_16x16x32_f16(aF, bF, acc[nt], 0, 0, 0);
        }
      }
#pragma unroll
      for (int nt = 0; nt < 8; ++nt) {
        float bvn = bias ? bias[nt * 16 + l15] : 0.f;
#pragma unroll
        for (int q = 0; q < 4; ++q) {
          float v = acc[nt][q] + bvn;
          if (ACT == 1) v = fmaxf(v, 0.f);
          acc[nt][q] = v;
        }
      }
      if constexpr (L2N) {
#pragma unroll
        for (int q = 0; q < 4; ++q) {
          float ss = 0.f;
#pragma unroll
          for (int nt = 0; nt < 8; ++nt) ss += acc[nt][q] * acc[nt][q];
          ss += __shfl_xor(ss, 1, 64); ss += __shfl_xor(ss, 2, 64);
          ss += __shfl_xor(ss, 4, 64); ss += __shfl_xor(ss, 8, 64);
          float inv = 1.f / fmaxf(sqrtf(ss), 1e-12f);
#pragma unroll
          for (int nt = 0; nt < 8; ++nt) acc[nt][q] *= inv;
        }
      }
    }
    if constexpr (POOL) {
      float ps[8];
#pragma unroll
      for (int nt = 0; nt < 8; ++nt) ps[nt] = 0.f;
      if (mt < 7) {
#pragma unroll
        for (int nt = 0; nt < 8; ++nt)
#pragma unroll
          for (int q = 0; q < 4; ++q) {
            int row = mt * 16 + lg * 4 + q;
            if (row < 100) ps[nt] += acc[nt][q];
          }
      }
#pragma unroll
      for (int nt = 0; nt < 8; ++nt) {
        ps[nt] += __shfl_xor(ps[nt], 16, 64);
        ps[nt] += __shfl_xor(ps[nt], 32, 64);
      }
      __syncthreads();                  // Ad dead -> scratch [8][128]
      if (mt < 7 && lg == 0)
#pragma unroll
        for (int nt = 0; nt < 8; ++nt) Ad[wv * 128 + nt * 16 + l15] = ps[nt];
      __syncthreads();
      if (tid < 128) {
        float s = 0.f;
        for (int w2 = 0; w2 < 7; ++w2) s += Ad[w2 * 128 + tid];
        OUT[(size_t)g * W + tid] = (OT)(s / 100.f);
      }
    } else {
      if (mt < 7) {
#pragma unroll
        for (int nt = 0; nt < 8; ++nt)
#pragma unroll
          for (int q = 0; q < 4; ++q) {
            int row = mt * 16 + lg * 4 + q;
            if (row < 100)
              OUT[(size_t)(base + row) * W + nt * 16 + l15] = (OT)acc[nt][q];
          }
      }
    }
  }
}

// ============ deterministic BatchNorm stats (50000 x 256), 2-stage ============
__global__ __launch_bounds__(256)
void bn_part_k(const float* __restrict__ X, float* __restrict__ P)
{
  const int b = blockIdx.x, c = threadIdx.x;
  const float* xb = X + (size_t)b * 250 * kH1;
  float s = 0.f, s2 = 0.f;
  for (int r = 0; r < 250; ++r) {
    float v = xb[(size_t)r * kH1 + c];
    s += v; s2 += v * v;
  }
  P[b * 512 + c] = s;
  P[b * 512 + 256 + c] = s2;
}
__global__ __launch_bounds__(256)
void bn_red_k(const float* __restrict__ P, float* __restrict__ stats)
{
  const int c = threadIdx.x;
  float s = 0.f, s2 = 0.f;
  for (int b = 0; b < 200; ++b) {
    s  += P[b * 512 + c];
    s2 += P[b * 512 + 256 + c];
  }
  float m = s / (float)kN;
  float v = s2 / (float)kN - m * m;
  stats[512 + c] = m;
  stats[768 + c] = rsqrtf(v + BN_EPS);
}

// column-parallel BN, in place
__global__ __launch_bounds__(64)
void bn_cols_k(float* __restrict__ X, int rows, int cols)
{
  const int c = blockIdx.x, t = threadIdx.x;
  float s = 0.f, s2 = 0.f;
  for (int r = t; r < rows; r += 64) {
    float v = X[(size_t)r * cols + c];
    s += v; s2 += v * v;
  }
#pragma unroll
  for (int o = 32; o; o >>= 1) { s += __shfl_xor(s, o, 64); s2 += __shfl_xor(s2, o, 64); }
  float m = s / (float)rows;
  float var = s2 / (float)rows - m * m;
  float rinv = rsqrtf(var + BN_EPS);
  for (int r = t; r < rows; r += 64)
    X[(size_t)r * cols + c] = (X[(size_t)r * cols + c] - m) * rinv;
}

// row-wise L2 normalize (128 cols) — target path only
__global__ __launch_bounds__(256)
void l2n_k(const float* __restrict__ X, float* __restrict__ Y, int rows)
{
  const int w = threadIdx.x >> 6, lane = threadIdx.x & 63;
  const int row = blockIdx.x * 4 + w;
  if (row >= rows) return;
  float2 v = *(const float2*)&X[(size_t)row * kH2 + lane * 2];
  float ss = v.x * v.x + v.y * v.y;
#pragma unroll
  for (int o = 32; o; o >>= 1) ss += __shfl_xor(ss, o, 64);
  float inv = 1.f / fmaxf(sqrtf(ss), 1e-12f);
  *(float2*)&Y[(size_t)row * kH2 + lane * 2] = make_float2(v.x * inv, v.y * inv);
}

__global__ __launch_bounds__(128)
void seg_max_k(const float* __restrict__ Z, const float* __restrict__ NOI,
               float* __restrict__ ZG, float* __restrict__ ZPG)
{
  const int g = blockIdx.x, c = threadIdx.x;
  const size_t b = (size_t)g * kNPG * kH2;
  float m1 = -INFINITY, m2 = -INFINITY;
  for (int r = 0; r < kNPG; ++r) {
    float v = Z[b + r * kH2 + c];
    float n = NOI[b + r * kH2 + c];
    m1 = fmaxf(m1, v);
    m2 = fmaxf(m2, v + n);
  }
  ZG[g * kH2 + c] = m1;
  ZPG[g * kH2 + c] = m2;
}

// =========================================================================
extern "C" void kernel_launch(void* const* d_in, const int* in_sizes, int n_in,
                              void* d_out, int out_size, void* d_ws, size_t ws_size,
                              hipStream_t stream)
{
  const float* x        = (const float*)d_in[0];
  const int*   srcI     = (const int*)d_in[1];
  const int*   dstI     = (const int*)d_in[2];
  const float* pos_x    = (const float*)d_in[4];
  const int*   psrc     = (const int*)d_in[5];
  const int*   pdst     = (const int*)d_in[6];
  const float* neg_x    = (const float*)d_in[8];
  const int*   nsrc     = (const int*)d_in[9];
  const int*   ndst     = (const int*)d_in[10];
  const float* target_x = (const float*)d_in[12];
  const float* noise    = (const float*)d_in[13];
  const float* W_enc1   = (const float*)d_in[14];
  const float* b_enc1   = (const float*)d_in[15];
  const float* W_enc2   = (const float*)d_in[16];
  const float* b_enc2   = (const float*)d_in[17];
  const float* W_dec1   = (const float*)d_in[18];
  const float* W_dec2   = (const float*)d_in[19];
  const float* Wn1      = (const float*)d_in[20];
  const float* bn1      = (const float*)d_in[21];
  const float* Wn2      = (const float*)d_in[22];
  const float* bn2      = (const float*)d_in[23];
  const float* Ws1      = (const float*)d_in[24];
  const float* bs1      = (const float*)d_in[25];
  const float* Wp1      = (const float*)d_in[26];
  const float* bp1      = (const float*)d_in[27];
  const float* Wp2      = (const float*)d_in[28];
  const float* bp2      = (const float*)d_in[29];

  float* out  = (float*)d_out;
  float* o_z   = out;                 // N x 128
  float* o_zg  = out + 6400000;       // 500 x 128
  float* o_xr  = out + 6464000;       // N x 128
  float* o_pos = out + 12864000;      // 500 x 128
  float* o_neg = out + 12928000;
  float* o_zgm = out + 12992000;
  float* o_zpm = out + 13056000;
  float* o_tz  = out + 13120000;

  // WORKSPACE MAP. Aliasing rule (r2-r4 lesson): a kernel must never read a
  // region while writing an overlapping one. bufA/bufB are disjoint.
  float* ws    = (float*)d_ws;
  float* bufA  = ws;                  // N x 256 region
  float* bufB  = ws + 12800000;       // N x 256 region
  float* stats = ws + 25600000;       // 1024 f32: [512..768)=mean [768..1024)=rinv
  float* t500  = ws + 25601024;       // 500 x 128
  float* t1    = t500 + 64000;        // 500 x 256
  float* t2    = t1 + 128000;         // 500 x 128
  float* zpg   = t2 + 64000;          // 500 x 128
  float* pstat = bufA;                // 200*512 f32; bufA dead there, consumed
                                      // by bn_red before bufA's next write
  _Float16* hA = (_Float16*)bufA;     // fp16 views (intermediates)
  _Float16* hB = (_Float16*)bufB;
  if (ws_size < (size_t)(25921024) * sizeof(float)) return;

  const dim3 gB(391, 2);   // M=50000, Nc=256
  const dim3 gC(391, 1);   // M=50000, Nc=128
  auto gg = [](int M, int Nc) {
    return dim3((unsigned)((M + 127) / 128), (unsigned)(Nc / 64), 1);
  };

  // ---------------- main encode ----------------
  gemm_mfma_k<0, 0, float, _Float16><<<gB, 256, 0, stream>>>(x, W_enc1, nullptr, hA, kN, kF0, kH1);
  gcn_agg_k<256, 1, 0, 0, 0, _Float16, float><<<kB, 512, kAggLds, stream>>>(hA, srcI, dstI, b_enc1, bufB, kEPG);
  bn_part_k<<<200, 256, 0, stream>>>(bufB, pstat);
  bn_red_k<<<1, 256, 0, stream>>>(pstat, stats);
  gemm_mfma_k<0, 1, float, _Float16><<<gC, 256, 0, stream>>>(bufB, W_enc2, stats + 512, hA, kN, kH1, kH2);
  gcn_agg_k<128, 0, 0, 1, 0, _Float16, float><<<kB, 512, kAggLds, stream>>>(hA, srcI, dstI, b_enc2, o_z, kEPG);
  // decode
  gemm_mfma_k<1, 0, float, _Float16><<<gB, 256, 0, stream>>>(o_z, W_dec1, nullptr, hA, kN, kH2, kH1);
  gemm_mfma_k<2, 0, _Float16, float><<<gC, 256, 0, stream>>>(hA, W_dec2, nullptr, o_xr, kN, kH1, kF0);
  // pooling + projection heads
  seg_max_k<<<kB, 128, 0, stream>>>(o_z, noise, o_zg, zpg);
  gemm_k<1><<<gg(kB, kH2), 256, 0, stream>>>(o_zg, Wp1, bp1, t500, kB, kH2, kH2);
  gemm_k<0><<<gg(kB, kH2), 256, 0, stream>>>(t500, Wp2, bp2, o_zgm, kB, kH2, kH2);
  gemm_k<1><<<gg(kB, kH2), 256, 0, stream>>>(zpg, Wp1, bp1, t500, kB, kH2, kH2);
  gemm_k<0><<<gg(kB, kH2), 256, 0, stream>>>(t500, Wp2, bp2, o_zpm, kB, kH2, kH2);

  // ---------------- positive subgraphs ----------------
  gemm_mfma_k<0, 0, float, _Float16><<<gB, 256, 0, stream>>>(pos_x, Ws1, nullptr, hA, kN, kF0, kH1);
  gcn_agg_k<256, 1, 1, 0, 0, _Float16, _Float16><<<kB, 512, kAggLds, stream>>>(hA, psrc, pdst, bs1, hB, kESG);
  gemm_mfma_k<0, 0, _Float16, _Float16><<<gC, 256, 0, stream>>>(hB, W_enc2, nullptr, hA, kN, kH1, kH2);
  gcn_agg_k<128, 0, 0, 1, 1, _Float16, float><<<kB, 512, kAggLds, stream>>>(hA, psrc, pdst, b_enc2, o_pos, kESG);

  // ---------------- negative subgraphs ----------------
  gemm_mfma_k<0, 0, float, _Float16><<<gB, 256, 0, stream>>>(neg_x, Ws1, nullptr, hA, kN, kF0, kH1);
  gcn_agg_k<256, 1, 1, 0, 0, _Float16, _Float16><<<kB, 512, kAggLds, stream>>>(hA, nsrc, ndst, bs1, hB, kESG);
  gemm_mfma_k<0, 0, _Float16, _Float16><<<gC, 256, 0, stream>>>(hB, W_enc2, nullptr, hA, kN, kH1, kH2);
  gcn_agg_k<128, 0, 0, 1, 1, _Float16, float><<<kB, 512, kAggLds, stream>>>(hA, nsrc, ndst, b_enc2, o_neg, kESG);

  // ---------------- target node encoder ----------------
  gemm_k<1><<<gg(kB, kH1), 256, 0, stream>>>(target_x, Wn1, bn1, t1, kB, kF0, kH1);
  bn_cols_k<<<256, 64, 0, stream>>>(t1, kB, kH1);
  gemm_k<0><<<gg(kB, kH2), 256, 0, stream>>>(t1, Wn2, bn2, t2, kB, kH1, kH2);
  l2n_k<<<125, 256, 0, stream>>>(t2, o_tz, kB);

  (void)in_sizes; (void)n_in; (void)out_size;
}

// Round 8
// 442.852 us; speedup vs baseline: 2.6793x; 1.1001x over previous
//
#include <hip/hip_runtime.h>
#include <math.h>

static constexpr int kN   = 50000;
static constexpr int kB   = 500;
static constexpr int kNPG = 100;
static constexpr int kEPG = 1600;
static constexpr int kESG = 800;
static constexpr int kF0  = 128;
static constexpr int kH1  = 256;
static constexpr int kH2  = 128;
#define BN_EPS 1e-5f

typedef _Float16 half8 __attribute__((ext_vector_type(8)));
typedef __attribute__((ext_vector_type(4))) float f32x4;

static constexpr int kAdS = 132;
static constexpr unsigned kAggLds = 112u * 132u * 4u;  // 59136 B

// ============ weight prep: W[K][Nc] f32 -> Wt[(kg*Nc + c)*8 + e] fp16 ============
// 5 segments of 32768 elems each (128 blocks x 256 thr per segment).
__global__ __launch_bounds__(256)
void wprep_k(const float* __restrict__ s0, const float* __restrict__ s1,
             const float* __restrict__ s2, const float* __restrict__ s3,
             const float* __restrict__ s4, _Float16* __restrict__ d)
{
  int seg = blockIdx.x >> 7;
  int idx = (blockIdx.x & 127) * 256 + threadIdx.x;   // 0..32767
  const float* S; int Nc;
  switch (seg) {
    case 0: S = s0; Nc = 256; break;
    case 1: S = s1; Nc = 128; break;
    case 2: S = s2; Nc = 256; break;
    case 3: S = s3; Nc = 128; break;
    default: S = s4; Nc = 256; break;
  }
  int e = idx & 7, t = idx >> 3;
  int c = t % Nc, kg = t / Nc;
  d[seg * 32768 + idx] = (_Float16)S[(size_t)(kg * 8 + e) * Nc + c];
}

// ================= direct-global fp16 MFMA GEMM (no LDS, no barriers) =================
// C = act(A @ W). A fp32 or fp16 (optionally BN-transform (a-mean)*rinv via tr),
// W given as Wt fragment layout (fp16, L2-hot). BM=128,BN=128, 4 waves, 4x4
// frags of mfma_f32_16x16x32_f16. Both operand frags are contiguous 16B/32B
// global loads; compiler software-pipelines freely (no barriers).
// NOTE: A and C must NOT alias (cross-block race — r2..r4 lesson).
template<int ACT, int TRANS, typename AT, typename OT>  // ACT 0=none 1=relu 2=sigmoid
__global__ __launch_bounds__(256)
void gemm_direct_k(const AT* __restrict__ A, const _Float16* __restrict__ Wt,
                   const float* __restrict__ tr, OT* __restrict__ C,
                   int M, int K, int Nc)
{
  const int tid = threadIdx.x;
  const int lane = tid & 63;
  const int l15 = lane & 15, lg = lane >> 4;
  const int wave = tid >> 6;
  const int wm = wave >> 1, wn = wave & 1;
  const int bm = blockIdx.x * 128;
  const int bn = blockIdx.y * 128;
  f32x4 acc[4][4];
#pragma unroll
  for (int m = 0; m < 4; ++m)
#pragma unroll
    for (int n = 0; n < 4; ++n) acc[m][n] = (f32x4){0.f, 0.f, 0.f, 0.f};

  int arow[4]; bool mok[4];
#pragma unroll
  for (int m = 0; m < 4; ++m) {
    arow[m] = bm + wm * 64 + m * 16 + l15;
    mok[m] = arow[m] < M;
  }
  const int bcol = bn + wn * 64 + l15;

  for (int k0 = 0; k0 < K; k0 += 32) {
    const int kb = k0 + lg * 8;
    // ---- B frags: contiguous 16B from Wt
    half8 bF[4];
#pragma unroll
    for (int n = 0; n < 4; ++n)
      bF[n] = *(const half8*)&Wt[((size_t)((k0 >> 3) + lg) * Nc + bcol + n * 16) * 8];
    // ---- A frags: contiguous 16B (fp16) or 32B (fp32) per m-tile
    half8 aF[4];
#pragma unroll
    for (int m = 0; m < 4; ++m) {
      half8 sa;
#pragma unroll
      for (int j = 0; j < 8; ++j) sa[j] = (_Float16)0.f;
      if (mok[m]) {
        if constexpr (sizeof(AT) == 4) {
          const float* ap = (const float*)A + (size_t)arow[m] * K + kb;
          float4 u0 = *(const float4*)ap, u1 = *(const float4*)(ap + 4);
          float va[8] = {u0.x, u0.y, u0.z, u0.w, u1.x, u1.y, u1.z, u1.w};
          if constexpr (TRANS) {
#pragma unroll
            for (int j = 0; j < 8; ++j) va[j] = (va[j] - tr[kb + j]) * tr[256 + kb + j];
          }
#pragma unroll
          for (int j = 0; j < 8; ++j) sa[j] = (_Float16)va[j];
        } else {
          half8 h = *(const half8*)((const _Float16*)A + (size_t)arow[m] * K + kb);
          if constexpr (TRANS) {
#pragma unroll
            for (int j = 0; j < 8; ++j)
              sa[j] = (_Float16)(((float)h[j] - tr[kb + j]) * tr[256 + kb + j]);
          } else {
            sa = h;
          }
        }
      }
      aF[m] = sa;
    }
#pragma unroll
    for (int m = 0; m < 4; ++m)
#pragma unroll
      for (int n = 0; n < 4; ++n)
        acc[m][n] = __builtin_amdgcn_mfma_f32_16x16x32_f16(aF[m], bF[n], acc[m][n], 0, 0, 0);
  }
  // epilogue: C/D layout col=lane&15, row=(lane>>4)*4+q
#pragma unroll
  for (int m = 0; m < 4; ++m) {
    int row_b = bm + wm * 64 + m * 16 + lg * 4;
#pragma unroll
    for (int q = 0; q < 4; ++q) {
      int row = row_b + q;
      if (row >= M) continue;
#pragma unroll
      for (int n = 0; n < 4; ++n) {
        float v = acc[m][n][q];
        if (ACT == 1) v = fmaxf(v, 0.f);
        else if (ACT == 2) v = 1.f / (1.f + expf(-v));
        C[(size_t)row * Nc + bn + wn * 64 + n * 16 + l15] = (OT)v;
      }
    }
  }
}

// ======================= small-M tiled f32 GEMM (M=500 paths) =======================
template<int ACT>
__global__ __launch_bounds__(256)
void gemm_k(const float* __restrict__ A, const float* __restrict__ W,
            const float* __restrict__ bias, float* __restrict__ C,
            int M, int K, int Nc)
{
  __shared__ float As[32][136];
  __shared__ float Ws[32][68];
  const int tid = threadIdx.x;
  const int bm = blockIdx.x * 128;
  const int bn = blockIdx.y * 64;
  const int tm = (tid & 15) * 8;
  const int tn = (tid >> 4) * 4;
  float acc[8][4];
#pragma unroll
  for (int i = 0; i < 8; ++i)
#pragma unroll
    for (int j = 0; j < 4; ++j) acc[i][j] = 0.f;

  for (int k0 = 0; k0 < K; k0 += 32) {
#pragma unroll
    for (int l = 0; l < 4; ++l) {
      int idx = tid + l * 256;
      int r = idx >> 3;
      int kq = (idx & 7) << 2;
      int gr = bm + r;
      float4 v = make_float4(0.f, 0.f, 0.f, 0.f);
      if (gr < M) v = *(const float4*)&A[(size_t)gr * K + k0 + kq];
      As[kq + 0][r] = v.x; As[kq + 1][r] = v.y;
      As[kq + 2][r] = v.z; As[kq + 3][r] = v.w;
    }
#pragma unroll
    for (int l = 0; l < 2; ++l) {
      int idx = tid + l * 256;
      int r = idx >> 4;
      int nq = (idx & 15) << 2;
      *(float4*)&Ws[r][nq] = *(const float4*)&W[(size_t)(k0 + r) * Nc + bn + nq];
    }
    __syncthreads();
#pragma unroll
    for (int kk = 0; kk < 32; ++kk) {
      float4 a0 = *(float4*)&As[kk][tm];
      float4 a1 = *(float4*)&As[kk][tm + 4];
      float4 w4 = *(float4*)&Ws[kk][tn];
      float am[8] = {a0.x, a0.y, a0.z, a0.w, a1.x, a1.y, a1.z, a1.w};
      float wn4[4] = {w4.x, w4.y, w4.z, w4.w};
#pragma unroll
      for (int i = 0; i < 8; ++i)
#pragma unroll
        for (int j = 0; j < 4; ++j) acc[i][j] += am[i] * wn4[j];
    }
    __syncthreads();
  }
  float4 bv = make_float4(0.f, 0.f, 0.f, 0.f);
  if (bias) bv = *(const float4*)&bias[bn + tn];
#pragma unroll
  for (int i = 0; i < 8; ++i) {
    int row = bm + tm + i;
    if (row >= M) break;
    float o0 = acc[i][0] + bv.x, o1 = acc[i][1] + bv.y;
    float o2 = acc[i][2] + bv.z, o3 = acc[i][3] + bv.w;
    if (ACT == 1) {
      o0 = fmaxf(o0, 0.f); o1 = fmaxf(o1, 0.f);
      o2 = fmaxf(o2, 0.f); o3 = fmaxf(o3, 0.f);
    } else if (ACT == 2) {
      o0 = 1.f / (1.f + expf(-o0)); o1 = 1.f / (1.f + expf(-o1));
      o2 = 1.f / (1.f + expf(-o2)); o3 = 1.f / (1.f + expf(-o3));
    }
    *(float4*)&C[(size_t)row * Nc + bn + tn] = make_float4(o0, o1, o2, o3);
  }
}

// ================= per-graph GCN aggregation, MFMA (fused tails) =================
template<int W, int ACT, int SEGBN, int L2N, int POOL, typename HT, typename OT>
__global__ __launch_bounds__(512, 4)
void gcn_agg_k(const HT* __restrict__ H, const int* __restrict__ srcI,
               const int* __restrict__ dstI, const float* __restrict__ bias,
               OT* __restrict__ OUT, int epg)
{
  extern __shared__ __align__(16) float lds[];
  float* Ad = lds;                      // [112][132]: Ad[d][s]
  __shared__ int scnt[kNPG];
  __shared__ float sdinv[kNPG];
  const int g = blockIdx.x, tid = threadIdx.x;
  const int base = g * kNPG;
  const size_t ebase = (size_t)g * epg;
  const int lane = tid & 63, wv = tid >> 6;
  const int l15 = lane & 15, lg = lane >> 4;

  for (int i = tid; i < 112 * kAdS; i += 512) Ad[i] = 0.f;
  if (tid < kNPG) scnt[tid] = 0;
  __syncthreads();
  for (int e = tid; e < epg; e += 512) atomicAdd(&scnt[dstI[ebase + e] - base], 1);
  __syncthreads();
  if (tid < kNPG) sdinv[tid] = rsqrtf((float)scnt[tid] + 1.f);
  __syncthreads();
  for (int e = tid; e < epg; e += 512) {
    int s = srcI[ebase + e] - base;
    int d = dstI[ebase + e] - base;
    atomicAdd(&Ad[d * kAdS + s], sdinv[s] * sdinv[d]);
  }
  __syncthreads();
  if (tid < kNPG) Ad[tid * kAdS + tid] += sdinv[tid] * sdinv[tid];
  __syncthreads();

  if constexpr (W == 256) {
    const int cbase = wv * 32;
    f32x4 acc[7][2];
#pragma unroll
    for (int mt = 0; mt < 7; ++mt) {
      acc[mt][0] = (f32x4){0.f, 0.f, 0.f, 0.f};
      acc[mt][1] = (f32x4){0.f, 0.f, 0.f, 0.f};
    }
#pragma unroll
    for (int k0 = 0; k0 < 128; k0 += 32) {
      half8 bF[2];
#pragma unroll
      for (int t = 0; t < 2; ++t) {
        int col = cbase + t * 16 + l15;
#pragma unroll
        for (int e = 0; e < 8; ++e) {
          int row = min(base + k0 + lg * 8 + e, kN - 1);
          bF[t][e] = (_Float16)H[(size_t)row * W + col];
        }
      }
#pragma unroll
      for (int mt = 0; mt < 7; ++mt) {
        const float* ap = &Ad[(mt * 16 + l15) * kAdS + k0 + lg * 8];
        f32x4 a0 = *(const f32x4*)ap;
        f32x4 a1 = *(const f32x4*)(ap + 4);
        half8 aF;
#pragma unroll
        for (int j = 0; j < 4; ++j) { aF[j] = (_Float16)a0[j]; aF[4 + j] = (_Float16)a1[j]; }
        acc[mt][0] = __builtin_amdgcn_mfma_f32_16x16x32_f16(aF, bF[0], acc[mt][0], 0, 0, 0);
        acc[mt][1] = __builtin_amdgcn_mfma_f32_16x16x32_f16(aF, bF[1], acc[mt][1], 0, 0, 0);
      }
    }
    float bv0 = bias ? bias[cbase + l15] : 0.f;
    float bv1 = bias ? bias[cbase + 16 + l15] : 0.f;
#pragma unroll
    for (int mt = 0; mt < 7; ++mt)
#pragma unroll
      for (int q = 0; q < 4; ++q) {
        float v0 = acc[mt][0][q] + bv0, v1 = acc[mt][1][q] + bv1;
        if (ACT == 1) { v0 = fmaxf(v0, 0.f); v1 = fmaxf(v1, 0.f); }
        acc[mt][0][q] = v0; acc[mt][1][q] = v1;
      }
    if constexpr (SEGBN) {
      float s0 = 0.f, s20 = 0.f, s1 = 0.f, s21 = 0.f;
#pragma unroll
      for (int mt = 0; mt < 7; ++mt)
#pragma unroll
        for (int q = 0; q < 4; ++q) {
          int row = mt * 16 + lg * 4 + q;
          if (row < 100) {
            float v0 = acc[mt][0][q], v1 = acc[mt][1][q];
            s0 += v0; s20 += v0 * v0; s1 += v1; s21 += v1 * v1;
          }
        }
      s0 += __shfl_xor(s0, 16, 64);  s0 += __shfl_xor(s0, 32, 64);
      s20 += __shfl_xor(s20, 16, 64); s20 += __shfl_xor(s20, 32, 64);
      s1 += __shfl_xor(s1, 16, 64);  s1 += __shfl_xor(s1, 32, 64);
      s21 += __shfl_xor(s21, 16, 64); s21 += __shfl_xor(s21, 32, 64);
      float m0 = s0 / 100.f, r0 = rsqrtf(s20 / 100.f - m0 * m0 + BN_EPS);
      float m1 = s1 / 100.f, r1 = rsqrtf(s21 / 100.f - m1 * m1 + BN_EPS);
#pragma unroll
      for (int mt = 0; mt < 7; ++mt)
#pragma unroll
        for (int q = 0; q < 4; ++q) {
          acc[mt][0][q] = (acc[mt][0][q] - m0) * r0;
          acc[mt][1][q] = (acc[mt][1][q] - m1) * r1;
        }
    }
#pragma unroll
    for (int mt = 0; mt < 7; ++mt)
#pragma unroll
      for (int q = 0; q < 4; ++q) {
        int row = mt * 16 + lg * 4 + q;
        if (row < 100) {
          OUT[(size_t)(base + row) * W + cbase + l15] = (OT)acc[mt][0][q];
          OUT[(size_t)(base + row) * W + cbase + 16 + l15] = (OT)acc[mt][1][q];
        }
      }
  } else {
    const int mt = wv;
    f32x4 acc[8];
#pragma unroll
    for (int nt = 0; nt < 8; ++nt) acc[nt] = (f32x4){0.f, 0.f, 0.f, 0.f};
    if (mt < 7) {
#pragma unroll
      for (int k0 = 0; k0 < 128; k0 += 32) {
        const float* ap = &Ad[(mt * 16 + l15) * kAdS + k0 + lg * 8];
        f32x4 a0 = *(const f32x4*)ap;
        f32x4 a1 = *(const f32x4*)(ap + 4);
        half8 aF;
#pragma unroll
        for (int j = 0; j < 4; ++j) { aF[j] = (_Float16)a0[j]; aF[4 + j] = (_Float16)a1[j]; }
#pragma unroll
        for (int nt = 0; nt < 8; ++nt) {
          half8 bF;
#pragma unroll
          for (int e = 0; e < 8; ++e) {
            int row = min(base + k0 + lg * 8 + e, kN - 1);
            bF[e] = (_Float16)H[(size_t)row * W + nt * 16 + l15];
          }
          acc[nt] = __builtin_amdgcn_mfma_f32_16x16x32_f16(aF, bF, acc[nt], 0, 0, 0);
        }
      }
#pragma unroll
      for (int nt = 0; nt < 8; ++nt) {
        float bvn = bias ? bias[nt * 16 + l15] : 0.f;
#pragma unroll
        for (int q = 0; q < 4; ++q) {
          float v = acc[nt][q] + bvn;
          if (ACT == 1) v = fmaxf(v, 0.f);
          acc[nt][q] = v;
        }
      }
      if constexpr (L2N) {
#pragma unroll
        for (int q = 0; q < 4; ++q) {
          float ss = 0.f;
#pragma unroll
          for (int nt = 0; nt < 8; ++nt) ss += acc[nt][q] * acc[nt][q];
          ss += __shfl_xor(ss, 1, 64); ss += __shfl_xor(ss, 2, 64);
          ss += __shfl_xor(ss, 4, 64); ss += __shfl_xor(ss, 8, 64);
          float inv = 1.f / fmaxf(sqrtf(ss), 1e-12f);
#pragma unroll
          for (int nt = 0; nt < 8; ++nt) acc[nt][q] *= inv;
        }
      }
    }
    if constexpr (POOL) {
      float ps[8];
#pragma unroll
      for (int nt = 0; nt < 8; ++nt) ps[nt] = 0.f;
      if (mt < 7) {
#pragma unroll
        for (int nt = 0; nt < 8; ++nt)
#pragma unroll
          for (int q = 0; q < 4; ++q) {
            int row = mt * 16 + lg * 4 + q;
            if (row < 100) ps[nt] += acc[nt][q];
          }
      }
#pragma unroll
      for (int nt = 0; nt < 8; ++nt) {
        ps[nt] += __shfl_xor(ps[nt], 16, 64);
        ps[nt] += __shfl_xor(ps[nt], 32, 64);
      }
      __syncthreads();
      if (mt < 7 && lg == 0)
#pragma unroll
        for (int nt = 0; nt < 8; ++nt) Ad[wv * 128 + nt * 16 + l15] = ps[nt];
      __syncthreads();
      if (tid < 128) {
        float s = 0.f;
        for (int w2 = 0; w2 < 7; ++w2) s += Ad[w2 * 128 + tid];
        OUT[(size_t)g * W + tid] = (OT)(s / 100.f);
      }
    } else {
      if (mt < 7) {
#pragma unroll
        for (int nt = 0; nt < 8; ++nt)
#pragma unroll
          for (int q = 0; q < 4; ++q) {
            int row = mt * 16 + lg * 4 + q;
            if (row < 100)
              OUT[(size_t)(base + row) * W + nt * 16 + l15] = (OT)acc[nt][q];
          }
      }
    }
  }
}

// ============ deterministic BatchNorm stats (50000 x 256 fp16), 2-stage ============
__global__ __launch_bounds__(256)
void bn_part_k(const _Float16* __restrict__ X, float* __restrict__ P)
{
  const int b = blockIdx.x, c = threadIdx.x;
  const _Float16* xb = X + (size_t)b * 250 * kH1;
  float s = 0.f, s2 = 0.f;
  for (int r = 0; r < 250; ++r) {
    float v = (float)xb[(size_t)r * kH1 + c];
    s += v; s2 += v * v;
  }
  P[b * 512 + c] = s;
  P[b * 512 + 256 + c] = s2;
}
__global__ __launch_bounds__(256)
void bn_red_k(const float* __restrict__ P, float* __restrict__ stats)
{
  const int c = threadIdx.x;
  float s = 0.f, s2 = 0.f;
  for (int b = 0; b < 200; ++b) {
    s  += P[b * 512 + c];
    s2 += P[b * 512 + 256 + c];
  }
  float m = s / (float)kN;
  float v = s2 / (float)kN - m * m;
  stats[512 + c] = m;
  stats[768 + c] = rsqrtf(v + BN_EPS);
}

// column-parallel BN, in place
__global__ __launch_bounds__(64)
void bn_cols_k(float* __restrict__ X, int rows, int cols)
{
  const int c = blockIdx.x, t = threadIdx.x;
  float s = 0.f, s2 = 0.f;
  for (int r = t; r < rows; r += 64) {
    float v = X[(size_t)r * cols + c];
    s += v; s2 += v * v;
  }
#pragma unroll
  for (int o = 32; o; o >>= 1) { s += __shfl_xor(s, o, 64); s2 += __shfl_xor(s2, o, 64); }
  float m = s / (float)rows;
  float var = s2 / (float)rows - m * m;
  float rinv = rsqrtf(var + BN_EPS);
  for (int r = t; r < rows; r += 64)
    X[(size_t)r * cols + c] = (X[(size_t)r * cols + c] - m) * rinv;
}

// row-wise L2 normalize (128 cols) — target path only
__global__ __launch_bounds__(256)
void l2n_k(const float* __restrict__ X, float* __restrict__ Y, int rows)
{
  const int w = threadIdx.x >> 6, lane = threadIdx.x & 63;
  const int row = blockIdx.x * 4 + w;
  if (row >= rows) return;
  float2 v = *(const float2*)&X[(size_t)row * kH2 + lane * 2];
  float ss = v.x * v.x + v.y * v.y;
#pragma unroll
  for (int o = 32; o; o >>= 1) ss += __shfl_xor(ss, o, 64);
  float inv = 1.f / fmaxf(sqrtf(ss), 1e-12f);
  *(float2*)&Y[(size_t)row * kH2 + lane * 2] = make_float2(v.x * inv, v.y * inv);
}

__global__ __launch_bounds__(128)
void seg_max_k(const float* __restrict__ Z, const float* __restrict__ NOI,
               float* __restrict__ ZG, float* __restrict__ ZPG)
{
  const int g = blockIdx.x, c = threadIdx.x;
  const size_t b = (size_t)g * kNPG * kH2;
  float m1 = -INFINITY, m2 = -INFINITY;
  for (int r = 0; r < kNPG; ++r) {
    float v = Z[b + r * kH2 + c];
    float n = NOI[b + r * kH2 + c];
    m1 = fmaxf(m1, v);
    m2 = fmaxf(m2, v + n);
  }
  ZG[g * kH2 + c] = m1;
  ZPG[g * kH2 + c] = m2;
}

// =========================================================================
extern "C" void kernel_launch(void* const* d_in, const int* in_sizes, int n_in,
                              void* d_out, int out_size, void* d_ws, size_t ws_size,
                              hipStream_t stream)
{
  const float* x        = (const float*)d_in[0];
  const int*   srcI     = (const int*)d_in[1];
  const int*   dstI     = (const int*)d_in[2];
  const float* pos_x    = (const float*)d_in[4];
  const int*   psrc     = (const int*)d_in[5];
  const int*   pdst     = (const int*)d_in[6];
  const float* neg_x    = (const float*)d_in[8];
  const int*   nsrc     = (const int*)d_in[9];
  const int*   ndst     = (const int*)d_in[10];
  const float* target_x = (const float*)d_in[12];
  const float* noise    = (const float*)d_in[13];
  const float* W_enc1   = (const float*)d_in[14];
  const float* b_enc1   = (const float*)d_in[15];
  const float* W_enc2   = (const float*)d_in[16];
  const float* b_enc2   = (const float*)d_in[17];
  const float* W_dec1   = (const float*)d_in[18];
  const float* W_dec2   = (const float*)d_in[19];
  const float* Wn1      = (const float*)d_in[20];
  const float* bn1      = (const float*)d_in[21];
  const float* Wn2      = (const float*)d_in[22];
  const float* bn2      = (const float*)d_in[23];
  const float* Ws1      = (const float*)d_in[24];
  const float* bs1      = (const float*)d_in[25];
  const float* Wp1      = (const float*)d_in[26];
  const float* bp1      = (const float*)d_in[27];
  const float* Wp2      = (const float*)d_in[28];
  const float* bp2      = (const float*)d_in[29];

  float* out  = (float*)d_out;
  float* o_z   = out;                 // N x 128
  float* o_zg  = out + 6400000;       // 500 x 128
  float* o_xr  = out + 6464000;       // N x 128
  float* o_pos = out + 12864000;      // 500 x 128
  float* o_neg = out + 12928000;
  float* o_zgm = out + 12992000;
  float* o_zpm = out + 13056000;
  float* o_tz  = out + 13120000;

  // WORKSPACE MAP (floats). hA/hB are fp16 views occupying only the first
  // 6.4M floats of each region; Wt and pstat sit in the unused upper halves.
  // Aliasing rule (r2-r4 lesson): no kernel reads a region while writing an
  // overlapping one. All GEMMs ping-pong hA <-> hB (disjoint).
  float* ws    = (float*)d_ws;
  float* bufA  = ws;                  // [0, 12.8M)
  float* bufB  = ws + 12800000;       // [12.8M, 25.6M)
  float* stats = ws + 25600000;       // 1024 f32
  float* t500  = ws + 25601024;
  float* t1    = t500 + 64000;        // 500 x 256
  float* t2    = t1 + 128000;
  float* zpg   = t2 + 64000;
  _Float16* hA  = (_Float16*)bufA;            // N x 256 fp16 = 6.4M floats
  _Float16* hB  = (_Float16*)bufB;
  _Float16* hWt = (_Float16*)(bufA + 7000000);  // 5 x 32768 fp16 = 81920 floats
  float*    pstat = bufB + 7000000;             // 200*512 f32
  if (ws_size < (size_t)(25921024) * sizeof(float)) return;

  _Float16* WtEnc1 = hWt;
  _Float16* WtEnc2 = hWt + 32768;
  _Float16* WtDec1 = hWt + 65536;
  _Float16* WtDec2 = hWt + 98304;
  _Float16* WtS1   = hWt + 131072;

  const dim3 gB(391, 2);   // M=50000, Nc=256
  const dim3 gC(391, 1);   // M=50000, Nc=128
  auto gg = [](int M, int Nc) {
    return dim3((unsigned)((M + 127) / 128), (unsigned)(Nc / 64), 1);
  };

  // ---------------- weight prep (runs every call; deterministic) ----------------
  wprep_k<<<640, 256, 0, stream>>>(W_enc1, W_enc2, W_dec1, W_dec2, Ws1, hWt);

  // ---------------- main encode ----------------
  gemm_direct_k<0, 0, float, _Float16><<<gB, 256, 0, stream>>>(x, WtEnc1, nullptr, hA, kN, kF0, kH1);
  gcn_agg_k<256, 1, 0, 0, 0, _Float16, _Float16><<<kB, 512, kAggLds, stream>>>(hA, srcI, dstI, b_enc1, hB, kEPG);
  bn_part_k<<<200, 256, 0, stream>>>(hB, pstat);
  bn_red_k<<<1, 256, 0, stream>>>(pstat, stats);
  gemm_direct_k<0, 1, _Float16, _Float16><<<gC, 256, 0, stream>>>(hB, WtEnc2, stats + 512, hA, kN, kH1, kH2);
  gcn_agg_k<128, 0, 0, 1, 0, _Float16, float><<<kB, 512, kAggLds, stream>>>(hA, srcI, dstI, b_enc2, o_z, kEPG);
  // decode
  gemm_direct_k<1, 0, float, _Float16><<<gB, 256, 0, stream>>>(o_z, WtDec1, nullptr, hA, kN, kH2, kH1);
  gemm_direct_k<2, 0, _Float16, float><<<gC, 256, 0, stream>>>(hA, WtDec2, nullptr, o_xr, kN, kH1, kF0);
  // pooling + projection heads
  seg_max_k<<<kB, 128, 0, stream>>>(o_z, noise, o_zg, zpg);
  gemm_k<1><<<gg(kB, kH2), 256, 0, stream>>>(o_zg, Wp1, bp1, t500, kB, kH2, kH2);
  gemm_k<0><<<gg(kB, kH2), 256, 0, stream>>>(t500, Wp2, bp2, o_zgm, kB, kH2, kH2);
  gemm_k<1><<<gg(kB, kH2), 256, 0, stream>>>(zpg, Wp1, bp1, t500, kB, kH2, kH2);
  gemm_k<0><<<gg(kB, kH2), 256, 0, stream>>>(t500, Wp2, bp2, o_zpm, kB, kH2, kH2);

  // ---------------- positive subgraphs ----------------
  gemm_direct_k<0, 0, float, _Float16><<<gB, 256, 0, stream>>>(pos_x, WtS1, nullptr, hA, kN, kF0, kH1);
  gcn_agg_k<256, 1, 1, 0, 0, _Float16, _Float16><<<kB, 512, kAggLds, stream>>>(hA, psrc, pdst, bs1, hB, kESG);
  gemm_direct_k<0, 0, _Float16, _Float16><<<gC, 256, 0, stream>>>(hB, WtEnc2, nullptr, hA, kN, kH1, kH2);
  gcn_agg_k<128, 0, 0, 1, 1, _Float16, float><<<kB, 512, kAggLds, stream>>>(hA, psrc, pdst, b_enc2, o_pos, kESG);

  // ---------------- negative subgraphs ----------------
  gemm_direct_k<0, 0, float, _Float16><<<gB, 256, 0, stream>>>(neg_x, WtS1, nullptr, hA, kN, kF0, kH1);
  gcn_agg_k<256, 1, 1, 0, 0, _Float16, _Float16><<<kB, 512, kAggLds, stream>>>(hA, nsrc, ndst, bs1, hB, kESG);
  gemm_direct_k<0, 0, _Float16, _Float16><<<gC, 256, 0, stream>>>(hB, WtEnc2, nullptr, hA, kN, kH1, kH2);
  gcn_agg_k<128, 0, 0, 1, 1, _Float16, float><<<kB, 512, kAggLds, stream>>>(hA, nsrc, ndst, b_enc2, o_neg, kESG);

  // ---------------- target node encoder ----------------
  gemm_k<1><<<gg(kB, kH1), 256, 0, stream>>>(target_x, Wn1, bn1, t1, kB, kF0, kH1);
  bn_cols_k<<<256, 64, 0, stream>>>(t1, kB, kH1);
  gemm_k<0><<<gg(kB, kH2), 256, 0, stream>>>(t1, Wn2, bn2, t2, kB, kH1, kH2);
  l2n_k<<<125, 256, 0, stream>>>(t2, o_tz, kB);

  (void)in_sizes; (void)n_in; (void)out_size;
}